// Round 9
// baseline (10501.848 us; speedup 1.0000x reference)
//
#include <hip/hip_runtime.h>
#include <math.h>

constexpr float LAM = 1.0f;
constexpr int   NIT = 20;
constexpr float TOL = 1e-6f;

typedef float f4 __attribute__((ext_vector_type(4)));

// ---------------- scal layout (floats) ----------------
// [0] flag (int) | [32..2080) S_PAP [8][256] | [2080..) 3x RS slot arrays [8][256]
#define S_PAP   32
#define S_RSB   2080
#define RSOFF(k) (S_RSB + (k) * 2048)
#define SCAL_F  (S_RSB + 3 * 2048)

__device__ __forceinline__ float dot8v(f4 a0, f4 a1, f4 b0, f4 b1){
  return a0[0]*b0[0] + a0[1]*b0[1] + a0[2]*b0[2] + a0[3]*b0[3]
       + a1[0]*b1[0] + a1[1]*b1[1] + a1[2]*b1[2] + a1[3]*b1[3];
}

// zero scal, zero cursor
__global__ void k_setup_nm(float* __restrict__ scal, int* __restrict__ cursor, int Mn){
  int i = blockIdx.x * blockDim.x + threadIdx.x;
  int stride = gridDim.x * blockDim.x;
  for (int j = i; j < SCAL_F; j += stride) scal[j] = 0.f;
  for (int j = i; j < Mn; j += stride) cursor[j] = 0;
}

__global__ void k_deg(const int* __restrict__ src, const int* __restrict__ dst,
                      int* __restrict__ cnt, int E){
  int i = blockIdx.x * blockDim.x + threadIdx.x;
  int stride = gridDim.x * blockDim.x;
  for (int e = i; e < E; e += stride){
    atomicAdd(&cnt[src[e]], 1);
    atomicAdd(&cnt[dst[e]], 1);
  }
}

// exclusive scan of degrees -> rowptr; cursor = rowptr
__global__ void k_scan(int* __restrict__ cnt, int* __restrict__ rowptr,
                       int* __restrict__ cursor, int Mn, int tot){
  __shared__ int sm[1024];
  const int T = 1024;
  int t = threadIdx.x;
  int chunk = (Mn + T - 1) / T;
  int lo = t * chunk, hi = lo + chunk; if (hi > Mn) hi = Mn;
  int s = 0;
  for (int i = lo; i < hi; ++i) s += cnt[i];
  sm[t] = s;
  __syncthreads();
  for (int o = 1; o < T; o <<= 1){
    int v = (t >= o) ? sm[t - o] : 0;
    __syncthreads();
    sm[t] += v;
    __syncthreads();
  }
  int base = (t == 0) ? 0 : sm[t - 1];
  for (int i = lo; i < hi; ++i){
    int c = cnt[i];
    rowptr[i] = base;
    cursor[i] = base;
    base += c;
  }
  if (t == T - 1) rowptr[Mn] = tot;
}

// fill CSR neighbor slots: pair[slot] = (partner, (e<<1)|side)
__global__ void k_fill(const int* __restrict__ src, const int* __restrict__ dst,
                       int* __restrict__ cursor, int2* __restrict__ pair, int E){
  int i = blockIdx.x * blockDim.x + threadIdx.x;
  int stride = gridDim.x * blockDim.x;
  for (int e = i; e < E; e += stride){
    int s = src[e], t = dst[e];
    int ps = atomicAdd(&cursor[s], 1);
    pair[ps] = make_int2(t, (e << 1));
    int pt = atomicAdd(&cursor[t], 1);
    pair[pt] = make_int2(s, (e << 1) | 1);
  }
}

// edge-order sequential M build: M[e] = Rs[e]^T Rd[e]. Pure stream, no atomics.
__global__ void k_medge(const float* __restrict__ Rs, const float* __restrict__ Rd,
                        float* __restrict__ Mb, int E){
  int g  = blockIdx.x * blockDim.x + threadIdx.x;
  int wv = g >> 6, l = g & 63;
  int nw = (gridDim.x * blockDim.x) >> 6;
  int d1 = l >> 3, d2 = l & 7;
  for (int e = wv; e < E; e += nw){
    float rs = Rs[(size_t)e * 64 + l];
    float rd = Rd[(size_t)e * 64 + l];
    float Mm = 0.f;
    #pragma unroll
    for (int a = 0; a < 8; ++a)
      Mm += __shfl(rs, a * 8 + d1, 64) * __shfl(rd, a * 8 + d2, 64);
    Mb[(size_t)e * 64 + l] = Mm;
  }
}

// D build (gather side): wave per node, lane l=(d1,d2).
__global__ void k_buildd(const float* __restrict__ Rs, const float* __restrict__ Rd,
                         const int* __restrict__ rowptr, const int2* __restrict__ pair,
                         float* __restrict__ Dd, int Mn){
  int g = blockIdx.x * blockDim.x + threadIdx.x;
  int v = g >> 6;
  if (v >= Mn) return;
  int l = g & 63, d1 = l >> 3, d2 = l & 7;
  float Dacc = 0.f;
  int j0 = rowptr[v], j1 = rowptr[v + 1];
  int j = j0;
  for (; j + 2 <= j1; j += 2){
    int e0 = pair[j].y, e1 = pair[j + 1].y;
    const float* R0 = (e0 & 1) ? Rd : Rs;
    const float* R1 = (e1 & 1) ? Rd : Rs;
    float x0 = R0[(size_t)(e0 >> 1) * 64 + l];
    float x1 = R1[(size_t)(e1 >> 1) * 64 + l];
    #pragma unroll
    for (int a = 0; a < 8; ++a){
      float p0 = __shfl(x0, a * 8 + d1, 64);
      float s0 = __shfl(x0, a * 8 + d2, 64);
      float p1 = __shfl(x1, a * 8 + d1, 64);
      float s1 = __shfl(x1, a * 8 + d2, 64);
      Dacc += p0 * s0 + p1 * s1;
    }
  }
  for (; j < j1; ++j){
    int e0 = pair[j].y;
    const float* R0 = (e0 & 1) ? Rd : Rs;
    float x0 = R0[(size_t)(e0 >> 1) * 64 + l];
    #pragma unroll
    for (int a = 0; a < 8; ++a)
      Dacc += __shfl(x0, a * 8 + d1, 64) * __shfl(x0, a * 8 + d2, 64);
  }
  Dd[(size_t)v * 64 + l] = ((d1 == d2) ? 1.f : 0.f) + LAM * Dacc;
}

// wave per node, lane=(b,dd). NO LDS. Direct global loads, depth-2 x 4-slot
// register pipeline. side0: M row (2xf4); side1: M column (8 dwords, coalesced
// across the 8 dd-lanes). Fused p.Ap partials into S_PAP.
__global__ void __launch_bounds__(256, 3)
k_mv(const float* __restrict__ Mb, const float* __restrict__ Dd,
     const int* __restrict__ rowptr, const int2* __restrict__ pair,
     const float* __restrict__ p, float* __restrict__ out,
     float* __restrict__ scal, int Mn){
  if (*(const int*)scal) return;
  int g = blockIdx.x * blockDim.x + threadIdx.x;
  int v = g >> 6;
  if (v >= Mn) return;
  int l = g & 63, b = l >> 3, dd = l & 7;
  int b8 = b * 8, d8 = dd * 8;
  int j1 = rowptr[v + 1];
  int j  = rowptr[v];

  const f4* pv4 = (const f4*)(p + (size_t)v * 64 + b8);
  f4 pv0 = pv4[0], pv1 = pv4[1];
  const f4* dr4 = (const f4*)(Dd + (size_t)v * 64 + d8);
  float acc = dot8v(dr4[0], dr4[1], pv0, pv1);

  const f4 fz = {0.f, 0.f, 0.f, 0.f};
  auto ldslot = [&](int jj, f4& q0, f4& q1, f4& m0, f4& m1){
    q0 = fz; q1 = fz; m0 = fz; m1 = fz;
    if (jj < j1){
      int2 ce = pair[jj];                       // wave-uniform
      const float* pc = p + (size_t)ce.x * 64 + b8;
      q0 = *(const f4*)pc; q1 = *(const f4*)(pc + 4);
      const float* Me = Mb + (size_t)(ce.y >> 1) * 64;
      if (!(ce.y & 1)){
        m0 = *(const f4*)(Me + d8);
        m1 = *(const f4*)(Me + d8 + 4);
      } else {
        m0[0] = Me[dd];      m0[1] = Me[dd + 8];
        m0[2] = Me[dd + 16]; m0[3] = Me[dd + 24];
        m1[0] = Me[dd + 32]; m1[1] = Me[dd + 40];
        m1[2] = Me[dd + 48]; m1[3] = Me[dd + 56];
      }
    }
  };

  f4 ap0,ap1,am0,am1, bp0,bp1,bm0,bm1, cp0,cp1,cm0,cm1, dp0,dp1,dm0,dm1;
  f4 ep0,ep1,em0,em1, fp0,fp1,fm0,fm1, gp0,gp1,gm0,gm1, hp0,hp1,hm0,hm1;

  ldslot(j,     ap0,ap1,am0,am1);
  ldslot(j + 1, bp0,bp1,bm0,bm1);
  ldslot(j + 2, cp0,cp1,cm0,cm1);
  ldslot(j + 3, dp0,dp1,dm0,dm1);
  j += 4;
  for (;;){
    bool more = (j < j1);
    if (more){
      ldslot(j,     ep0,ep1,em0,em1);
      ldslot(j + 1, fp0,fp1,fm0,fm1);
      ldslot(j + 2, gp0,gp1,gm0,gm1);
      ldslot(j + 3, hp0,hp1,hm0,hm1);
      j += 4;
    }
    acc -= LAM * (dot8v(am0,am1,ap0,ap1) + dot8v(bm0,bm1,bp0,bp1)
                + dot8v(cm0,cm1,cp0,cp1) + dot8v(dm0,dm1,dp0,dp1));
    if (!more) break;
    bool more2 = (j < j1);
    if (more2){
      ldslot(j,     ap0,ap1,am0,am1);
      ldslot(j + 1, bp0,bp1,bm0,bm1);
      ldslot(j + 2, cp0,cp1,cm0,cm1);
      ldslot(j + 3, dp0,dp1,dm0,dm1);
      j += 4;
    }
    acc -= LAM * (dot8v(em0,em1,ep0,ep1) + dot8v(fm0,fm1,fp0,fp1)
                + dot8v(gm0,gm1,gp0,gp1) + dot8v(hm0,hm1,hp0,hp1));
    if (!more2) break;
  }

  out[(size_t)v * 64 + l] = acc;
  // fused p.Ap partial: p element at (v, b*8+dd) from pv regs
  float pself = (dd & 4) ? ((dd & 2) ? ((dd & 1) ? pv1[3] : pv1[2])
                                     : ((dd & 1) ? pv1[1] : pv1[0]))
                         : ((dd & 2) ? ((dd & 1) ? pv0[3] : pv0[2])
                                     : ((dd & 1) ? pv0[1] : pv0[0]));
  float part = pself * acc;
  part += __shfl_xor(part, 1, 64);
  part += __shfl_xor(part, 2, 64);
  part += __shfl_xor(part, 4, 64);
  if (dd == 0)
    atomicAdd(&scal[S_PAP + b * 256 + (blockIdx.x & 255)], part);
}

// c0 (batch-major) -> node-major buffer
__global__ void k_perm(const float* __restrict__ c0, float* __restrict__ xp, int Mn){
  int i = blockIdx.x * blockDim.x + threadIdx.x;
  int n4 = Mn * 16;
  if (i >= n4) return;
  int v = i >> 4, rem = i & 15, b = rem >> 1, half = rem & 1;
  f4 cv = *(const f4*)(c0 + ((size_t)b * Mn + v) * 8 + half * 4);
  ((f4*)xp)[i] = cv;
}

// r = c0p - Ap; p = r (in place); x(batch-major, d_out) = c0;
// r.r partials -> RS0; blocks 0..7 zero S_PAP (clears mv(c0)'s p.Ap garbage)
__global__ void k_init_nm(float* __restrict__ p, const float* __restrict__ Ap,
                          float* __restrict__ r, float* __restrict__ x_bm,
                          float* __restrict__ scal, int n4tot, int Mn){
  int t = threadIdx.x;
  if (blockIdx.x < 8) scal[S_PAP + blockIdx.x * 256 + t] = 0.f;
  int i = blockIdx.x * blockDim.x + t;
  int l = t & 63;
  float part = 0.f;
  if (i < n4tot){
    f4 cv = ((const f4*)p)[i];
    f4 av = ((const f4*)Ap)[i];
    f4 rv = cv - av;
    ((f4*)r)[i] = rv;
    ((f4*)p)[i] = rv;
    int v = i >> 4, rem = i & 15, b = rem >> 1, half = rem & 1;
    ((f4*)x_bm)[((size_t)b * Mn + v) * 2 + half] = cv;
    part = rv[0]*rv[0] + rv[1]*rv[1] + rv[2]*rv[2] + rv[3]*rv[3];
  }
  part += __shfl_xor(part, 1, 64);
  part += __shfl_xor(part, 16, 64);
  part += __shfl_xor(part, 32, 64);
  if ((l & 49) == 0)
    atomicAdd(&scal[RSOFF(0) + ((l >> 1) & 7) * 256 + (blockIdx.x & 255)], part);
}

// x += a p; r -= a Ap; rnew.rnew -> RS[wr]. alpha = sum(RS[ro]) / sum(S_PAP).
__global__ void k_upd_nm(float* __restrict__ x_bm, float* __restrict__ r,
                         const float* __restrict__ p, const float* __restrict__ Ap,
                         float* __restrict__ scal, int n4tot, int Mn,
                         int ro, int wr){
  if (*(const int*)scal) return;
  __shared__ float sal[8];
  int t = threadIdx.x;
  if (t < 8){
    float sp = 0.f, so = 0.f;
    const float* pp = scal + S_PAP + t * 256;
    const float* po = scal + ro + t * 256;
    #pragma unroll 4
    for (int k = 0; k < 256; ++k){ sp += pp[k]; so += po[k]; }
    sal[t] = so / (sp + 1e-12f);
  }
  __syncthreads();
  int i = blockIdx.x * blockDim.x + t;
  int l = t & 63;
  float part = 0.f;
  if (i < n4tot){
    int v = i >> 4, rem = i & 15, b = rem >> 1, half = rem & 1;
    float al = sal[b];
    size_t xi = ((size_t)b * Mn + v) * 2 + half;
    f4 pv = ((const f4*)p)[i];
    f4 av = ((const f4*)Ap)[i];
    f4 xv = ((f4*)x_bm)[xi];
    f4 rv = ((f4*)r)[i];
    xv += al * pv;
    rv -= al * av;
    ((f4*)x_bm)[xi] = xv;
    ((f4*)r)[i] = rv;
    part = rv[0]*rv[0] + rv[1]*rv[1] + rv[2]*rv[2] + rv[3]*rv[3];
  }
  part += __shfl_xor(part, 1, 64);
  part += __shfl_xor(part, 16, 64);
  part += __shfl_xor(part, 32, 64);
  if ((l & 49) == 0)
    atomicAdd(&scal[wr + ((l >> 1) & 7) * 256 + (blockIdx.x & 255)], part);
}

// p = r + beta p with beta = sum(RS[cur])/sum(RS[prev]); conv check sets flag
// (p frozen at conv iteration). Blocks 0..7 zero S_PAP, 8..15 zero RS[zr].
__global__ void k_pupd_nm(const float* __restrict__ r, float* __restrict__ p,
                          float* __restrict__ scal, int n4tot,
                          int cur, int prev, int zr){
  if (*(const int*)scal) return;
  __shared__ float sbeta[8];
  __shared__ float srs[8];
  __shared__ int sconv;
  int t = threadIdx.x;
  if (t < 8){
    float sc = 0.f, sp = 0.f;
    const float* pc = scal + cur + t * 256;
    const float* pv = scal + prev + t * 256;
    #pragma unroll 4
    for (int k = 0; k < 256; ++k){ sc += pc[k]; sp += pv[k]; }
    sbeta[t] = sc / (sp + 1e-12f);
    srs[t] = sc;
  }
  __syncthreads();
  if (t == 0){
    float ssum = srs[0]+srs[1]+srs[2]+srs[3]+srs[4]+srs[5]+srs[6]+srs[7];
    sconv = (sqrtf(ssum / 8.0f) < TOL) ? 1 : 0;
    if (sconv && blockIdx.x == 0) *(int*)scal = 1;   // freeze (same value all blocks)
  }
  __syncthreads();
  // distributed zeroing for next iteration (disjoint from cur/prev)
  if (blockIdx.x < 8)        scal[S_PAP + blockIdx.x * 256 + t] = 0.f;
  else if (blockIdx.x < 16)  scal[zr + (blockIdx.x - 8) * 256 + t] = 0.f;
  if (sconv) return;                                  // frozen: keep old p
  int i = blockIdx.x * blockDim.x + t;
  if (i >= n4tot) return;
  int b = (i >> 1) & 7;
  float be = sbeta[b];
  f4 rv = ((const f4*)r)[i];
  f4 pv = ((f4*)p)[i];
  pv = rv + be * pv;
  ((f4*)p)[i] = pv;
}

// ---------------- minimal fallback tier (batch-major, R-direct) ----------------
#define OS_RSOLD 0
#define OS_PAP   8
#define OS_RSNEW 16
#define OS_ALPHA 24
#define OS_BETA  32
#define OS_FLAG  40

__device__ __forceinline__ float blk_reduce_256(float v){
  __shared__ float sm[4];
  #pragma unroll
  for (int o = 32; o > 0; o >>= 1) v += __shfl_down(v, o, 64);
  int lane = threadIdx.x & 63, w = threadIdx.x >> 6;
  if (lane == 0) sm[w] = v;
  __syncthreads();
  return (threadIdx.x == 0) ? (sm[0] + sm[1] + sm[2] + sm[3]) : 0.f;
}

__global__ void k_setup_fb(float* scal){
  int i = blockIdx.x * blockDim.x + threadIdx.x;
  if (i < 64) scal[i] = 0.f;
}

__global__ void k_apinit(const float* __restrict__ in, float* __restrict__ out,
                         int n4tot, const int* __restrict__ flag){
  if (*flag) return;
  int j = blockIdx.x * blockDim.x + threadIdx.x;
  if (j < n4tot) ((f4*)out)[j] = ((const f4*)in)[j];
}

__global__ void k_mv_edge_fb(const float* __restrict__ Rs, const float* __restrict__ Rd,
                             const int* __restrict__ src, const int* __restrict__ dst,
                             const float* __restrict__ in, float* __restrict__ out,
                             int Mn, int E, const int* __restrict__ flag){
  if (*flag) return;
  int g  = blockIdx.x * blockDim.x + threadIdx.x;
  int wv = g >> 6, l = g & 63;
  int nw = (gridDim.x * blockDim.x) >> 6;
  int b = l >> 3, q = l & 7;
  for (int e = wv; e < E; e += nw){
    int s = src[e], t = dst[e];
    const f4* rs4 = (const f4*)(Rs + (size_t)e * 64 + q * 8);
    const f4* rd4 = (const f4*)(Rd + (size_t)e * 64 + q * 8);
    const f4* ps4 = (const f4*)(in + ((size_t)b * Mn + s) * 8);
    const f4* pd4 = (const f4*)(in + ((size_t)b * Mn + t) * 8);
    f4 ra0 = rs4[0], ra1 = rs4[1], pa0 = ps4[0], pa1 = ps4[1];
    f4 rb0 = rd4[0], rb1 = rd4[1], pb0 = pd4[0], pb1 = pd4[1];
    float re = dot8v(ra0, ra1, pa0, pa1) - dot8v(rb0, rb1, pb0, pb1);
    float cs = 0.f, cd = 0.f;
    #pragma unroll
    for (int a = 0; a < 8; ++a){
      float rea = __shfl(re, b * 8 + a, 64);
      cs += Rs[(size_t)e * 64 + a * 8 + q] * rea;
      cd += Rd[(size_t)e * 64 + a * 8 + q] * rea;
    }
    atomicAdd(&out[((size_t)b * Mn + s) * 8 + q],  LAM * cs);
    atomicAdd(&out[((size_t)b * Mn + t) * 8 + q], -LAM * cd);
  }
}

__global__ void k_init_o(const float* __restrict__ c0, const float* __restrict__ Ap,
                         float* __restrict__ x, float* __restrict__ r, float* __restrict__ p,
                         float* scal, int n4){
  int b = blockIdx.y;
  size_t base = (size_t)b * n4;
  int j = blockIdx.x * blockDim.x + threadIdx.x;
  float part = 0.f;
  if (j < n4){
    f4 cv = ((const f4*)c0)[base + j];
    f4 av = ((const f4*)Ap)[base + j];
    f4 rv = cv - av;
    ((f4*)x)[base + j] = cv;
    ((f4*)r)[base + j] = rv;
    ((f4*)p)[base + j] = rv;
    part = rv[0]*rv[0] + rv[1]*rv[1] + rv[2]*rv[2] + rv[3]*rv[3];
  }
  float tot = blk_reduce_256(part);
  if (threadIdx.x == 0) atomicAdd(&scal[OS_RSOLD + b], tot);
}

__global__ void k_dot_o(const float* __restrict__ p, const float* __restrict__ Ap,
                        float* scal, int n4){
  const int* flag = (const int*)(scal + OS_FLAG);
  if (*flag) return;
  int b = blockIdx.y;
  size_t base = (size_t)b * n4;
  int j = blockIdx.x * blockDim.x + threadIdx.x;
  float part = 0.f;
  if (j < n4){
    f4 pv = ((const f4*)p)[base + j];
    f4 av = ((const f4*)Ap)[base + j];
    part = pv[0]*av[0] + pv[1]*av[1] + pv[2]*av[2] + pv[3]*av[3];
  }
  float tot = blk_reduce_256(part);
  if (threadIdx.x == 0) atomicAdd(&scal[OS_PAP + b], tot);
}

__global__ void k_s1_o(float* scal){
  const int* flag = (const int*)(scal + OS_FLAG);
  if (*flag) return;
  int t = threadIdx.x;
  if (t < 8){
    scal[OS_ALPHA + t] = scal[OS_RSOLD + t] / (scal[OS_PAP + t] + 1e-12f);
    scal[OS_RSNEW + t] = 0.f;
  }
}

__global__ void k_upd_o(float* __restrict__ x, float* __restrict__ r,
                        const float* __restrict__ p, const float* __restrict__ Ap,
                        float* scal, int n4){
  const int* flag = (const int*)(scal + OS_FLAG);
  if (*flag) return;
  int b = blockIdx.y;
  size_t base = (size_t)b * n4;
  float al = scal[OS_ALPHA + b];
  int j = blockIdx.x * blockDim.x + threadIdx.x;
  float part = 0.f;
  if (j < n4){
    f4 pv = ((const f4*)p)[base + j];
    f4 av = ((const f4*)Ap)[base + j];
    f4 xv = ((f4*)x)[base + j];
    f4 rv = ((f4*)r)[base + j];
    xv += al * pv;
    rv -= al * av;
    ((f4*)x)[base + j] = xv;
    ((f4*)r)[base + j] = rv;
    part = rv[0]*rv[0] + rv[1]*rv[1] + rv[2]*rv[2] + rv[3]*rv[3];
  }
  float tot = blk_reduce_256(part);
  if (threadIdx.x == 0) atomicAdd(&scal[OS_RSNEW + b], tot);
}

__global__ void k_s2_o(float* scal){
  int* flag = (int*)(scal + OS_FLAG);
  if (*flag) return;
  if (threadIdx.x == 0){
    float ssum = 0.f;
    for (int bb = 0; bb < 8; ++bb) ssum += scal[OS_RSNEW + bb];
    if (sqrtf(ssum / 8.0f) < TOL){
      *flag = 1;
    } else {
      for (int bb = 0; bb < 8; ++bb){
        scal[OS_BETA + bb]  = scal[OS_RSNEW + bb] / (scal[OS_RSOLD + bb] + 1e-12f);
        scal[OS_RSOLD + bb] = scal[OS_RSNEW + bb];
        scal[OS_PAP + bb]   = 0.f;
      }
    }
  }
}

__global__ void k_pupd_o(const float* __restrict__ r, float* __restrict__ p,
                         float* scal, int n4){
  const int* flag = (const int*)(scal + OS_FLAG);
  if (*flag) return;
  int b = blockIdx.y;
  size_t base = (size_t)b * n4;
  float be = scal[OS_BETA + b];
  int j = blockIdx.x * blockDim.x + threadIdx.x;
  if (j < n4){
    f4 rv = ((const f4*)r)[base + j];
    f4 pv = ((f4*)p)[base + j];
    pv = rv + be * pv;
    ((f4*)p)[base + j] = pv;
  }
}

// ---------------- launch ----------------
extern "C" void kernel_launch(void* const* d_in, const int* in_sizes, int n_in,
                              void* d_out, int out_size, void* d_ws, size_t ws_size,
                              hipStream_t stream){
  const float* c0  = (const float*)d_in[0];
  const int*   src = (const int*)d_in[1];
  const int*   dst = (const int*)d_in[2];
  const float* Rs  = (const float*)d_in[3];
  const float* Rd  = (const float*)d_in[4];

  int N  = in_sizes[0];          // B*Mn*8 floats, B=8, d=8
  int Mn = N / 64;
  int E  = in_sizes[1];
  int n4tot = N / 4;
  int twoE = 2 * E;

  float* ws = (float*)d_ws;
  size_t off = 0;
  float* r    = ws + off;  off += N;
  float* p    = ws + off;  off += N;
  float* Ap   = ws + off;  off += N;
  float* scal = ws + off;  off += SCAL_F;
  float* Dd   = ws + off;  off += (size_t)Mn * 64;
  int* rowptr = (int*)(ws + off);  off += (size_t)((Mn + 1 + 3) & ~3);
  int* cursor = (int*)(ws + off);  off += (size_t)((Mn + 3) & ~3);
  int2* pair  = (int2*)(ws + off); off += (size_t)2 * twoE;   // 2E int2
  float* Mb   = ws + off;  off += (size_t)E * 64;
  size_t need_main = off * 4;

  int nb_vec  = (n4tot + 255) / 256;
  int nb_node = (Mn * 64 + 255) / 256;

  if (ws_size >= need_main){
    k_setup_nm<<<512, 256, 0, stream>>>(scal, cursor, Mn);
    k_deg  <<<1024, 256, 0, stream>>>(src, dst, cursor, E);
    k_scan <<<1, 1024, 0, stream>>>(cursor, rowptr, cursor, Mn, twoE);
    k_fill <<<1024, 256, 0, stream>>>(src, dst, cursor, pair, E);
    k_medge<<<4096, 256, 0, stream>>>(Rs, Rd, Mb, E);
    k_buildd<<<nb_node, 256, 0, stream>>>(Rs, Rd, rowptr, pair, Dd, Mn);

    float* x_bm = (float*)d_out;
    k_perm<<<nb_vec, 256, 0, stream>>>(c0, p, Mn);   // p := c0 (node-major)
    k_mv<<<nb_node, 256, 0, stream>>>(Mb, Dd, rowptr, pair, p, Ap, scal, Mn);
    k_init_nm<<<nb_vec, 256, 0, stream>>>(p, Ap, r, x_bm, scal, n4tot, Mn);

    for (int it = 0; it < NIT; ++it){
      int ro = RSOFF(it % 3), wr = RSOFF((it + 1) % 3), zr = RSOFF((it + 2) % 3);
      k_mv<<<nb_node, 256, 0, stream>>>(Mb, Dd, rowptr, pair, p, Ap, scal, Mn);
      k_upd_nm<<<nb_vec, 256, 0, stream>>>(x_bm, r, p, Ap, scal, n4tot, Mn, ro, wr);
      k_pupd_nm<<<nb_vec, 256, 0, stream>>>(r, p, scal, n4tot, wr, ro, zr);
    }
  } else {
    // fallback: batch-major R-direct (needs 3N+64 floats)
    float* fr    = ws;
    float* fp    = fr + N;
    float* fAp   = fp + N;
    float* fscal = fAp + N;
    const int* flagp = (const int*)(fscal + OS_FLAG);
    int n4 = Mn * 2;
    dim3 vgrid((n4 + 255) / 256, 8);
    int cb = (n4tot + 255) / 256;
    float* x = (float*)d_out;

    k_setup_fb<<<1, 64, 0, stream>>>(fscal);
    k_apinit<<<cb, 256, 0, stream>>>(c0, fAp, n4tot, flagp);
    k_mv_edge_fb<<<2048, 256, 0, stream>>>(Rs, Rd, src, dst, c0, fAp, Mn, E, flagp);
    k_init_o<<<vgrid, 256, 0, stream>>>(c0, fAp, x, fr, fp, fscal, n4);
    for (int it = 0; it < NIT; ++it){
      k_apinit<<<cb, 256, 0, stream>>>(fp, fAp, n4tot, flagp);
      k_mv_edge_fb<<<2048, 256, 0, stream>>>(Rs, Rd, src, dst, fp, fAp, Mn, E, flagp);
      k_dot_o<<<vgrid, 256, 0, stream>>>(fp, fAp, fscal, n4);
      k_s1_o<<<1, 64, 0, stream>>>(fscal);
      k_upd_o<<<vgrid, 256, 0, stream>>>(x, fr, fp, fAp, fscal, n4);
      k_s2_o<<<1, 64, 0, stream>>>(fscal);
      k_pupd_o<<<vgrid, 256, 0, stream>>>(fr, fp, fscal, n4);
    }
  }
}

// Round 10
// 5572.166 us; speedup vs baseline: 1.8847x; 1.8847x over previous
//
#include <hip/hip_runtime.h>
#include <math.h>

constexpr float LAM = 1.0f;
constexpr int   NIT = 20;
constexpr float TOL = 1e-6f;

typedef float f4 __attribute__((ext_vector_type(4)));

// ---------------- scal layout (floats) ----------------
// [0] flag (int) | [32..2080) S_PAP [8][256] | [2080..) 3x RS slot arrays [8][256]
#define S_PAP   32
#define S_RSB   2080
#define RSOFF(k) (S_RSB + (k) * 2048)
#define SCAL_F  (S_RSB + 3 * 2048)

__device__ __forceinline__ float dot8v(f4 a0, f4 a1, f4 b0, f4 b1){
  return a0[0]*b0[0] + a0[1]*b0[1] + a0[2]*b0[2] + a0[3]*b0[3]
       + a1[0]*b1[0] + a1[1]*b1[1] + a1[2]*b1[2] + a1[3]*b1[3];
}

// zero scal, zero cursor
__global__ void k_setup_nm(float* __restrict__ scal, int* __restrict__ cursor, int Mn){
  int i = blockIdx.x * blockDim.x + threadIdx.x;
  int stride = gridDim.x * blockDim.x;
  for (int j = i; j < SCAL_F; j += stride) scal[j] = 0.f;
  for (int j = i; j < Mn; j += stride) cursor[j] = 0;
}

__global__ void k_deg(const int* __restrict__ src, const int* __restrict__ dst,
                      int* __restrict__ cnt, int E){
  int i = blockIdx.x * blockDim.x + threadIdx.x;
  int stride = gridDim.x * blockDim.x;
  for (int e = i; e < E; e += stride){
    atomicAdd(&cnt[src[e]], 1);
    atomicAdd(&cnt[dst[e]], 1);
  }
}

// exclusive scan of degrees -> rowptr; cursor = rowptr
__global__ void k_scan(int* __restrict__ cnt, int* __restrict__ rowptr,
                       int* __restrict__ cursor, int Mn, int tot){
  __shared__ int sm[1024];
  const int T = 1024;
  int t = threadIdx.x;
  int chunk = (Mn + T - 1) / T;
  int lo = t * chunk, hi = lo + chunk; if (hi > Mn) hi = Mn;
  int s = 0;
  for (int i = lo; i < hi; ++i) s += cnt[i];
  sm[t] = s;
  __syncthreads();
  for (int o = 1; o < T; o <<= 1){
    int v = (t >= o) ? sm[t - o] : 0;
    __syncthreads();
    sm[t] += v;
    __syncthreads();
  }
  int base = (t == 0) ? 0 : sm[t - 1];
  for (int i = lo; i < hi; ++i){
    int c = cnt[i];
    rowptr[i] = base;
    cursor[i] = base;
    base += c;
  }
  if (t == T - 1) rowptr[Mn] = tot;
}

// fill CSR neighbor slots: pair[slot] = (partner, (e<<1)|side)
__global__ void k_fill(const int* __restrict__ src, const int* __restrict__ dst,
                       int* __restrict__ cursor, int2* __restrict__ pair, int E){
  int i = blockIdx.x * blockDim.x + threadIdx.x;
  int stride = gridDim.x * blockDim.x;
  for (int e = i; e < E; e += stride){
    int s = src[e], t = dst[e];
    int ps = atomicAdd(&cursor[s], 1);
    pair[ps] = make_int2(t, (e << 1));
    int pt = atomicAdd(&cursor[t], 1);
    pair[pt] = make_int2(s, (e << 1) | 1);
  }
}

// edge-order sequential M build: M[e] = Rs[e]^T Rd[e]. Pure stream, no atomics.
__global__ void k_medge(const float* __restrict__ Rs, const float* __restrict__ Rd,
                        float* __restrict__ Mb, int E){
  int g  = blockIdx.x * blockDim.x + threadIdx.x;
  int wv = g >> 6, l = g & 63;
  int nw = (gridDim.x * blockDim.x) >> 6;
  int d1 = l >> 3, d2 = l & 7;
  for (int e = wv; e < E; e += nw){
    float rs = Rs[(size_t)e * 64 + l];
    float rd = Rd[(size_t)e * 64 + l];
    float Mm = 0.f;
    #pragma unroll
    for (int a = 0; a < 8; ++a)
      Mm += __shfl(rs, a * 8 + d1, 64) * __shfl(rd, a * 8 + d2, 64);
    Mb[(size_t)e * 64 + l] = Mm;
  }
}

// D build (gather side): wave per node, lane l=(d1,d2).
__global__ void k_buildd(const float* __restrict__ Rs, const float* __restrict__ Rd,
                         const int* __restrict__ rowptr, const int2* __restrict__ pair,
                         float* __restrict__ Dd, int Mn){
  int g = blockIdx.x * blockDim.x + threadIdx.x;
  int v = g >> 6;
  if (v >= Mn) return;
  int l = g & 63, d1 = l >> 3, d2 = l & 7;
  float Dacc = 0.f;
  int j0 = rowptr[v], j1 = rowptr[v + 1];
  int j = j0;
  for (; j + 2 <= j1; j += 2){
    int e0 = pair[j].y, e1 = pair[j + 1].y;
    const float* R0 = (e0 & 1) ? Rd : Rs;
    const float* R1 = (e1 & 1) ? Rd : Rs;
    float x0 = R0[(size_t)(e0 >> 1) * 64 + l];
    float x1 = R1[(size_t)(e1 >> 1) * 64 + l];
    #pragma unroll
    for (int a = 0; a < 8; ++a){
      float p0 = __shfl(x0, a * 8 + d1, 64);
      float s0 = __shfl(x0, a * 8 + d2, 64);
      float p1 = __shfl(x1, a * 8 + d1, 64);
      float s1 = __shfl(x1, a * 8 + d2, 64);
      Dacc += p0 * s0 + p1 * s1;
    }
  }
  for (; j < j1; ++j){
    int e0 = pair[j].y;
    const float* R0 = (e0 & 1) ? Rd : Rs;
    float x0 = R0[(size_t)(e0 >> 1) * 64 + l];
    #pragma unroll
    for (int a = 0; a < 8; ++a)
      Dacc += __shfl(x0, a * 8 + d1, 64) * __shfl(x0, a * 8 + d2, 64);
  }
  Dd[(size_t)v * 64 + l] = ((d1 == d2) ? 1.f : 0.f) + LAM * Dacc;
}

// wave per node. Single-LDS-buffer + register-prefetch M-form matvec
// (round-8 structure, proven 184us). LDS rows padded to 68 floats.
// No __syncthreads: each wave touches only its own LDS slice.
__global__ void k_mv(const float* __restrict__ Mb, const float* __restrict__ Dd,
                     const int* __restrict__ rowptr, const int2* __restrict__ pair,
                     const float* __restrict__ p, float* __restrict__ out,
                     float* __restrict__ scal, int Mn){
  if (*(const int*)scal) return;
  __shared__ float pbuf[4][8][68];
  __shared__ float mbuf[4][8][68];
  __shared__ int   cbuf[4][128];
  __shared__ int   ebuf[4][128];
  int g = blockIdx.x * blockDim.x + threadIdx.x;
  int v = g >> 6;
  if (v >= Mn) return;
  int w  = threadIdx.x >> 6;
  int l  = g & 63;
  int hi = l >> 3, lo = l & 7;
  int k8 = lo * 8;          // phase-A segment offset / phase-B row offset (dd*8)
  int b8 = hi * 8;          // phase-B batch offset
  int j0 = rowptr[v];
  int rowlen = rowptr[v + 1] - j0;

  // stage pair for this wave's row (wave-synchronous LDS, no barrier needed)
  for (int jj = l; jj < rowlen && jj < 128; jj += 64){
    int2 ce = pair[j0 + jj];
    cbuf[w][jj] = ce.x;
    ebuf[w][jj] = ce.y;
  }

  int nch = (rowlen + 7) >> 3;

  auto gaddr = [&](int n, int& c, int& e){
    int jj = n * 8 + hi;
    c = v; e = 0;
    if (jj < rowlen){
      if (jj < 128){ c = cbuf[w][jj]; e = ebuf[w][jj] >> 1; }
      else         { int2 ce = pair[j0 + jj]; c = ce.x; e = ce.y >> 1; }
    }
  };

  // acc = D_v p_v   (D row dd=lo; p row b=hi)
  const f4* pv4 = (const f4*)(p + (size_t)v * 64 + b8);
  f4 pv0 = pv4[0], pv1 = pv4[1];
  const f4* dr4 = (const f4*)(Dd + (size_t)v * 64 + k8);
  float acc = dot8v(dr4[0], dr4[1], pv0, pv1);

  f4 gp0, gp1, gm0, gm1;
  if (nch > 0){
    int c, e; gaddr(0, c, e);
    const float* pc = p + (size_t)c * 64 + k8;
    gp0 = *(const f4*)pc; gp1 = *(const f4*)(pc + 4);
    const float* mc = Mb + (size_t)e * 64 + k8;
    gm0 = *(const f4*)mc; gm1 = *(const f4*)(mc + 4);
  }

  for (int n = 0; n < nch; ++n){
    // commit prefetched chunk to LDS (in-order DS: after prior chunk's reads)
    float* dp = &pbuf[w][hi][k8];
    *(f4*)dp = gp0; *(f4*)(dp + 4) = gp1;
    float* dm = &mbuf[w][hi][k8];
    *(f4*)dm = gm0; *(f4*)(dm + 4) = gm1;
    // issue next chunk's gathers (latency hides under this chunk's compute)
    bool more = (n + 1 < nch);
    if (more){
      int c, e; gaddr(n + 1, c, e);
      const float* pc = p + (size_t)c * 64 + k8;
      gp0 = *(const f4*)pc; gp1 = *(const f4*)(pc + 4);
      const float* mc = Mb + (size_t)e * 64 + k8;
      gm0 = *(const f4*)mc; gm1 = *(const f4*)(mc + 4);
    }
    int jb = n * 8;
    int lim = rowlen - jb;
    if (lim >= 8){
      #pragma unroll
      for (int q = 0; q < 8; ++q){
        int jj = jb + q;                                       // wave-uniform
        int sd = ((jj < 128) ? ebuf[w][jj] : pair[j0 + jj].y) & 1;
        const float* pr = &pbuf[w][q][b8];
        f4 q0 = *(const f4*)pr, q1 = *(const f4*)(pr + 4);
        const float* mc = &mbuf[w][q][0];
        if (!sd){
          f4 m0 = *(const f4*)(mc + k8);
          f4 m1 = *(const f4*)(mc + k8 + 4);
          acc -= LAM * dot8v(m0, m1, q0, q1);
        } else {
          acc -= LAM * ( mc[lo]      * q0[0] + mc[lo +  8] * q0[1]
                       + mc[lo + 16] * q0[2] + mc[lo + 24] * q0[3]
                       + mc[lo + 32] * q1[0] + mc[lo + 40] * q1[1]
                       + mc[lo + 48] * q1[2] + mc[lo + 56] * q1[3]);
        }
      }
    } else {
      #pragma unroll
      for (int q = 0; q < 8; ++q){
        if (q < lim){
          int jj = jb + q;
          int sd = ((jj < 128) ? ebuf[w][jj] : pair[j0 + jj].y) & 1;
          const float* pr = &pbuf[w][q][b8];
          f4 q0 = *(const f4*)pr, q1 = *(const f4*)(pr + 4);
          const float* mc = &mbuf[w][q][0];
          if (!sd){
            f4 m0 = *(const f4*)(mc + k8);
            f4 m1 = *(const f4*)(mc + k8 + 4);
            acc -= LAM * dot8v(m0, m1, q0, q1);
          } else {
            acc -= LAM * ( mc[lo]      * q0[0] + mc[lo +  8] * q0[1]
                         + mc[lo + 16] * q0[2] + mc[lo + 24] * q0[3]
                         + mc[lo + 32] * q1[0] + mc[lo + 40] * q1[1]
                         + mc[lo + 48] * q1[2] + mc[lo + 56] * q1[3]);
          }
        }
      }
    }
  }
  out[(size_t)v * 64 + l] = acc;
  // fused p.Ap partial: p element at (v, hi*8+lo) from pv regs
  float pself = (lo & 4) ? ((lo & 2) ? ((lo & 1) ? pv1[3] : pv1[2])
                                     : ((lo & 1) ? pv1[1] : pv1[0]))
                         : ((lo & 2) ? ((lo & 1) ? pv0[3] : pv0[2])
                                     : ((lo & 1) ? pv0[1] : pv0[0]));
  float part = pself * acc;
  part += __shfl_xor(part, 1, 64);
  part += __shfl_xor(part, 2, 64);
  part += __shfl_xor(part, 4, 64);
  if (lo == 0)
    atomicAdd(&scal[S_PAP + hi * 256 + (blockIdx.x & 255)], part);
}

// c0 (batch-major) -> node-major buffer
__global__ void k_perm(const float* __restrict__ c0, float* __restrict__ xp, int Mn){
  int i = blockIdx.x * blockDim.x + threadIdx.x;
  int n4 = Mn * 16;
  if (i >= n4) return;
  int v = i >> 4, rem = i & 15, b = rem >> 1, half = rem & 1;
  f4 cv = *(const f4*)(c0 + ((size_t)b * Mn + v) * 8 + half * 4);
  ((f4*)xp)[i] = cv;
}

// r = c0p - Ap; p = r (in place); x(batch-major, d_out) = c0;
// r.r partials -> RS0; blocks 0..7 zero S_PAP (clears mv(c0)'s p.Ap garbage)
__global__ void k_init_nm(float* __restrict__ p, const float* __restrict__ Ap,
                          float* __restrict__ r, float* __restrict__ x_bm,
                          float* __restrict__ scal, int n4tot, int Mn){
  int t = threadIdx.x;
  if (blockIdx.x < 8) scal[S_PAP + blockIdx.x * 256 + t] = 0.f;
  int i = blockIdx.x * blockDim.x + t;
  int l = t & 63;
  float part = 0.f;
  if (i < n4tot){
    f4 cv = ((const f4*)p)[i];
    f4 av = ((const f4*)Ap)[i];
    f4 rv = cv - av;
    ((f4*)r)[i] = rv;
    ((f4*)p)[i] = rv;
    int v = i >> 4, rem = i & 15, b = rem >> 1, half = rem & 1;
    ((f4*)x_bm)[((size_t)b * Mn + v) * 2 + half] = cv;
    part = rv[0]*rv[0] + rv[1]*rv[1] + rv[2]*rv[2] + rv[3]*rv[3];
  }
  part += __shfl_xor(part, 1, 64);
  part += __shfl_xor(part, 16, 64);
  part += __shfl_xor(part, 32, 64);
  if ((l & 49) == 0)
    atomicAdd(&scal[RSOFF(0) + ((l >> 1) & 7) * 256 + (blockIdx.x & 255)], part);
}

// x += a p; r -= a Ap; rnew.rnew -> RS[wr]. alpha = sum(RS[ro]) / sum(S_PAP).
__global__ void k_upd_nm(float* __restrict__ x_bm, float* __restrict__ r,
                         const float* __restrict__ p, const float* __restrict__ Ap,
                         float* __restrict__ scal, int n4tot, int Mn,
                         int ro, int wr){
  if (*(const int*)scal) return;
  __shared__ float sal[8];
  int t = threadIdx.x;
  if (t < 8){
    float sp = 0.f, so = 0.f;
    const float* pp = scal + S_PAP + t * 256;
    const float* po = scal + ro + t * 256;
    #pragma unroll 4
    for (int k = 0; k < 256; ++k){ sp += pp[k]; so += po[k]; }
    sal[t] = so / (sp + 1e-12f);
  }
  __syncthreads();
  int i = blockIdx.x * blockDim.x + t;
  int l = t & 63;
  float part = 0.f;
  if (i < n4tot){
    int v = i >> 4, rem = i & 15, b = rem >> 1, half = rem & 1;
    float al = sal[b];
    size_t xi = ((size_t)b * Mn + v) * 2 + half;
    f4 pv = ((const f4*)p)[i];
    f4 av = ((const f4*)Ap)[i];
    f4 xv = ((f4*)x_bm)[xi];
    f4 rv = ((f4*)r)[i];
    xv += al * pv;
    rv -= al * av;
    ((f4*)x_bm)[xi] = xv;
    ((f4*)r)[i] = rv;
    part = rv[0]*rv[0] + rv[1]*rv[1] + rv[2]*rv[2] + rv[3]*rv[3];
  }
  part += __shfl_xor(part, 1, 64);
  part += __shfl_xor(part, 16, 64);
  part += __shfl_xor(part, 32, 64);
  if ((l & 49) == 0)
    atomicAdd(&scal[wr + ((l >> 1) & 7) * 256 + (blockIdx.x & 255)], part);
}

// p = r + beta p with beta = sum(RS[cur])/sum(RS[prev]); conv check sets flag
// (p frozen at conv iteration). Blocks 0..7 zero S_PAP, 8..15 zero RS[zr].
__global__ void k_pupd_nm(const float* __restrict__ r, float* __restrict__ p,
                          float* __restrict__ scal, int n4tot,
                          int cur, int prev, int zr){
  if (*(const int*)scal) return;
  __shared__ float sbeta[8];
  __shared__ float srs[8];
  __shared__ int sconv;
  int t = threadIdx.x;
  if (t < 8){
    float sc = 0.f, sp = 0.f;
    const float* pc = scal + cur + t * 256;
    const float* pv = scal + prev + t * 256;
    #pragma unroll 4
    for (int k = 0; k < 256; ++k){ sc += pc[k]; sp += pv[k]; }
    sbeta[t] = sc / (sp + 1e-12f);
    srs[t] = sc;
  }
  __syncthreads();
  if (t == 0){
    float ssum = srs[0]+srs[1]+srs[2]+srs[3]+srs[4]+srs[5]+srs[6]+srs[7];
    sconv = (sqrtf(ssum / 8.0f) < TOL) ? 1 : 0;
    if (sconv && blockIdx.x == 0) *(int*)scal = 1;   // freeze (same value all blocks)
  }
  __syncthreads();
  // distributed zeroing for next iteration (disjoint from cur/prev)
  if (blockIdx.x < 8)        scal[S_PAP + blockIdx.x * 256 + t] = 0.f;
  else if (blockIdx.x < 16)  scal[zr + (blockIdx.x - 8) * 256 + t] = 0.f;
  if (sconv) return;                                  // frozen: keep old p
  int i = blockIdx.x * blockDim.x + t;
  if (i >= n4tot) return;
  int b = (i >> 1) & 7;
  float be = sbeta[b];
  f4 rv = ((const f4*)r)[i];
  f4 pv = ((f4*)p)[i];
  pv = rv + be * pv;
  ((f4*)p)[i] = pv;
}

// ---------------- minimal fallback tier (batch-major, R-direct) ----------------
#define OS_RSOLD 0
#define OS_PAP   8
#define OS_RSNEW 16
#define OS_ALPHA 24
#define OS_BETA  32
#define OS_FLAG  40

__device__ __forceinline__ float blk_reduce_256(float v){
  __shared__ float sm[4];
  #pragma unroll
  for (int o = 32; o > 0; o >>= 1) v += __shfl_down(v, o, 64);
  int lane = threadIdx.x & 63, w = threadIdx.x >> 6;
  if (lane == 0) sm[w] = v;
  __syncthreads();
  return (threadIdx.x == 0) ? (sm[0] + sm[1] + sm[2] + sm[3]) : 0.f;
}

__global__ void k_setup_fb(float* scal){
  int i = blockIdx.x * blockDim.x + threadIdx.x;
  if (i < 64) scal[i] = 0.f;
}

__global__ void k_apinit(const float* __restrict__ in, float* __restrict__ out,
                         int n4tot, const int* __restrict__ flag){
  if (*flag) return;
  int j = blockIdx.x * blockDim.x + threadIdx.x;
  if (j < n4tot) ((f4*)out)[j] = ((const f4*)in)[j];
}

__global__ void k_mv_edge_fb(const float* __restrict__ Rs, const float* __restrict__ Rd,
                             const int* __restrict__ src, const int* __restrict__ dst,
                             const float* __restrict__ in, float* __restrict__ out,
                             int Mn, int E, const int* __restrict__ flag){
  if (*flag) return;
  int g  = blockIdx.x * blockDim.x + threadIdx.x;
  int wv = g >> 6, l = g & 63;
  int nw = (gridDim.x * blockDim.x) >> 6;
  int b = l >> 3, q = l & 7;
  for (int e = wv; e < E; e += nw){
    int s = src[e], t = dst[e];
    const f4* rs4 = (const f4*)(Rs + (size_t)e * 64 + q * 8);
    const f4* rd4 = (const f4*)(Rd + (size_t)e * 64 + q * 8);
    const f4* ps4 = (const f4*)(in + ((size_t)b * Mn + s) * 8);
    const f4* pd4 = (const f4*)(in + ((size_t)b * Mn + t) * 8);
    f4 ra0 = rs4[0], ra1 = rs4[1], pa0 = ps4[0], pa1 = ps4[1];
    f4 rb0 = rd4[0], rb1 = rd4[1], pb0 = pd4[0], pb1 = pd4[1];
    float re = dot8v(ra0, ra1, pa0, pa1) - dot8v(rb0, rb1, pb0, pb1);
    float cs = 0.f, cd = 0.f;
    #pragma unroll
    for (int a = 0; a < 8; ++a){
      float rea = __shfl(re, b * 8 + a, 64);
      cs += Rs[(size_t)e * 64 + a * 8 + q] * rea;
      cd += Rd[(size_t)e * 64 + a * 8 + q] * rea;
    }
    atomicAdd(&out[((size_t)b * Mn + s) * 8 + q],  LAM * cs);
    atomicAdd(&out[((size_t)b * Mn + t) * 8 + q], -LAM * cd);
  }
}

__global__ void k_init_o(const float* __restrict__ c0, const float* __restrict__ Ap,
                         float* __restrict__ x, float* __restrict__ r, float* __restrict__ p,
                         float* scal, int n4){
  int b = blockIdx.y;
  size_t base = (size_t)b * n4;
  int j = blockIdx.x * blockDim.x + threadIdx.x;
  float part = 0.f;
  if (j < n4){
    f4 cv = ((const f4*)c0)[base + j];
    f4 av = ((const f4*)Ap)[base + j];
    f4 rv = cv - av;
    ((f4*)x)[base + j] = cv;
    ((f4*)r)[base + j] = rv;
    ((f4*)p)[base + j] = rv;
    part = rv[0]*rv[0] + rv[1]*rv[1] + rv[2]*rv[2] + rv[3]*rv[3];
  }
  float tot = blk_reduce_256(part);
  if (threadIdx.x == 0) atomicAdd(&scal[OS_RSOLD + b], tot);
}

__global__ void k_dot_o(const float* __restrict__ p, const float* __restrict__ Ap,
                        float* scal, int n4){
  const int* flag = (const int*)(scal + OS_FLAG);
  if (*flag) return;
  int b = blockIdx.y;
  size_t base = (size_t)b * n4;
  int j = blockIdx.x * blockDim.x + threadIdx.x;
  float part = 0.f;
  if (j < n4){
    f4 pv = ((const f4*)p)[base + j];
    f4 av = ((const f4*)Ap)[base + j];
    part = pv[0]*av[0] + pv[1]*av[1] + pv[2]*av[2] + pv[3]*av[3];
  }
  float tot = blk_reduce_256(part);
  if (threadIdx.x == 0) atomicAdd(&scal[OS_PAP + b], tot);
}

__global__ void k_s1_o(float* scal){
  const int* flag = (const int*)(scal + OS_FLAG);
  if (*flag) return;
  int t = threadIdx.x;
  if (t < 8){
    scal[OS_ALPHA + t] = scal[OS_RSOLD + t] / (scal[OS_PAP + t] + 1e-12f);
    scal[OS_RSNEW + t] = 0.f;
  }
}

__global__ void k_upd_o(float* __restrict__ x, float* __restrict__ r,
                        const float* __restrict__ p, const float* __restrict__ Ap,
                        float* scal, int n4){
  const int* flag = (const int*)(scal + OS_FLAG);
  if (*flag) return;
  int b = blockIdx.y;
  size_t base = (size_t)b * n4;
  float al = scal[OS_ALPHA + b];
  int j = blockIdx.x * blockDim.x + threadIdx.x;
  float part = 0.f;
  if (j < n4){
    f4 pv = ((const f4*)p)[base + j];
    f4 av = ((const f4*)Ap)[base + j];
    f4 xv = ((f4*)x)[base + j];
    f4 rv = ((f4*)r)[base + j];
    xv += al * pv;
    rv -= al * av;
    ((f4*)x)[base + j] = xv;
    ((f4*)r)[base + j] = rv;
    part = rv[0]*rv[0] + rv[1]*rv[1] + rv[2]*rv[2] + rv[3]*rv[3];
  }
  float tot = blk_reduce_256(part);
  if (threadIdx.x == 0) atomicAdd(&scal[OS_RSNEW + b], tot);
}

__global__ void k_s2_o(float* scal){
  int* flag = (int*)(scal + OS_FLAG);
  if (*flag) return;
  if (threadIdx.x == 0){
    float ssum = 0.f;
    for (int bb = 0; bb < 8; ++bb) ssum += scal[OS_RSNEW + bb];
    if (sqrtf(ssum / 8.0f) < TOL){
      *flag = 1;
    } else {
      for (int bb = 0; bb < 8; ++bb){
        scal[OS_BETA + bb]  = scal[OS_RSNEW + bb] / (scal[OS_RSOLD + bb] + 1e-12f);
        scal[OS_RSOLD + bb] = scal[OS_RSNEW + bb];
        scal[OS_PAP + bb]   = 0.f;
      }
    }
  }
}

__global__ void k_pupd_o(const float* __restrict__ r, float* __restrict__ p,
                         float* scal, int n4){
  const int* flag = (const int*)(scal + OS_FLAG);
  if (*flag) return;
  int b = blockIdx.y;
  size_t base = (size_t)b * n4;
  float be = scal[OS_BETA + b];
  int j = blockIdx.x * blockDim.x + threadIdx.x;
  if (j < n4){
    f4 rv = ((const f4*)r)[base + j];
    f4 pv = ((f4*)p)[base + j];
    pv = rv + be * pv;
    ((f4*)p)[base + j] = pv;
  }
}

// ---------------- launch ----------------
extern "C" void kernel_launch(void* const* d_in, const int* in_sizes, int n_in,
                              void* d_out, int out_size, void* d_ws, size_t ws_size,
                              hipStream_t stream){
  const float* c0  = (const float*)d_in[0];
  const int*   src = (const int*)d_in[1];
  const int*   dst = (const int*)d_in[2];
  const float* Rs  = (const float*)d_in[3];
  const float* Rd  = (const float*)d_in[4];

  int N  = in_sizes[0];          // B*Mn*8 floats, B=8, d=8
  int Mn = N / 64;
  int E  = in_sizes[1];
  int n4tot = N / 4;
  int twoE = 2 * E;

  float* ws = (float*)d_ws;
  size_t off = 0;
  float* r    = ws + off;  off += N;
  float* p    = ws + off;  off += N;
  float* Ap   = ws + off;  off += N;
  float* scal = ws + off;  off += SCAL_F;
  float* Dd   = ws + off;  off += (size_t)Mn * 64;
  int* rowptr = (int*)(ws + off);  off += (size_t)((Mn + 1 + 3) & ~3);
  int* cursor = (int*)(ws + off);  off += (size_t)((Mn + 3) & ~3);
  int2* pair  = (int2*)(ws + off); off += (size_t)2 * twoE;   // 2E int2
  float* Mb   = ws + off;  off += (size_t)E * 64;
  size_t need_main = off * 4;

  int nb_vec  = (n4tot + 255) / 256;
  int nb_node = (Mn * 64 + 255) / 256;

  if (ws_size >= need_main){
    k_setup_nm<<<512, 256, 0, stream>>>(scal, cursor, Mn);
    k_deg  <<<1024, 256, 0, stream>>>(src, dst, cursor, E);
    k_scan <<<1, 1024, 0, stream>>>(cursor, rowptr, cursor, Mn, twoE);
    k_fill <<<1024, 256, 0, stream>>>(src, dst, cursor, pair, E);
    k_medge<<<4096, 256, 0, stream>>>(Rs, Rd, Mb, E);
    k_buildd<<<nb_node, 256, 0, stream>>>(Rs, Rd, rowptr, pair, Dd, Mn);

    float* x_bm = (float*)d_out;
    k_perm<<<nb_vec, 256, 0, stream>>>(c0, p, Mn);   // p := c0 (node-major)
    k_mv<<<nb_node, 256, 0, stream>>>(Mb, Dd, rowptr, pair, p, Ap, scal, Mn);
    k_init_nm<<<nb_vec, 256, 0, stream>>>(p, Ap, r, x_bm, scal, n4tot, Mn);

    for (int it = 0; it < NIT; ++it){
      int ro = RSOFF(it % 3), wr = RSOFF((it + 1) % 3), zr = RSOFF((it + 2) % 3);
      k_mv<<<nb_node, 256, 0, stream>>>(Mb, Dd, rowptr, pair, p, Ap, scal, Mn);
      k_upd_nm<<<nb_vec, 256, 0, stream>>>(x_bm, r, p, Ap, scal, n4tot, Mn, ro, wr);
      k_pupd_nm<<<nb_vec, 256, 0, stream>>>(r, p, scal, n4tot, wr, ro, zr);
    }
  } else {
    // fallback: batch-major R-direct (needs 3N+64 floats)
    float* fr    = ws;
    float* fp    = fr + N;
    float* fAp   = fp + N;
    float* fscal = fAp + N;
    const int* flagp = (const int*)(fscal + OS_FLAG);
    int n4 = Mn * 2;
    dim3 vgrid((n4 + 255) / 256, 8);
    int cb = (n4tot + 255) / 256;
    float* x = (float*)d_out;

    k_setup_fb<<<1, 64, 0, stream>>>(fscal);
    k_apinit<<<cb, 256, 0, stream>>>(c0, fAp, n4tot, flagp);
    k_mv_edge_fb<<<2048, 256, 0, stream>>>(Rs, Rd, src, dst, c0, fAp, Mn, E, flagp);
    k_init_o<<<vgrid, 256, 0, stream>>>(c0, fAp, x, fr, fp, fscal, n4);
    for (int it = 0; it < NIT; ++it){
      k_apinit<<<cb, 256, 0, stream>>>(fp, fAp, n4tot, flagp);
      k_mv_edge_fb<<<2048, 256, 0, stream>>>(Rs, Rd, src, dst, fp, fAp, Mn, E, flagp);
      k_dot_o<<<vgrid, 256, 0, stream>>>(fp, fAp, fscal, n4);
      k_s1_o<<<1, 64, 0, stream>>>(fscal);
      k_upd_o<<<vgrid, 256, 0, stream>>>(x, fr, fp, fAp, fscal, n4);
      k_s2_o<<<1, 64, 0, stream>>>(fscal);
      k_pupd_o<<<vgrid, 256, 0, stream>>>(fr, fp, fscal, n4);
    }
  }
}

// Round 11
// 5448.415 us; speedup vs baseline: 1.9275x; 1.0227x over previous
//
#include <hip/hip_runtime.h>
#include <math.h>

constexpr float LAM = 1.0f;
constexpr int   NIT = 20;
constexpr float TOL = 1e-6f;

typedef float f4 __attribute__((ext_vector_type(4)));

// ---------------- scal layout (floats) ----------------
#define S_RSOLD 0
#define S_ALPHA 8
#define S_BETA  16
#define S_FLAG  24        // int alias
#define S_PAP   32        // [8][256] partial slots for p.Ap
#define S_RS    (32+2048) // [8][256] partial slots for r.r
#define SCAL_F  (32+4096)

__device__ __forceinline__ float dot8v(f4 a0, f4 a1, f4 b0, f4 b1){
  return a0[0]*b0[0] + a0[1]*b0[1] + a0[2]*b0[2] + a0[3]*b0[3]
       + a1[0]*b1[0] + a1[1]*b1[1] + a1[2]*b1[2] + a1[3]*b1[3];
}

// zero scal, zero cursor, D := I
__global__ void k_setup_nm(float* __restrict__ D, float* __restrict__ scal,
                           int* __restrict__ cursor, int Mn){
  int i = blockIdx.x * blockDim.x + threadIdx.x;
  int stride = gridDim.x * blockDim.x;
  for (int j = i; j < SCAL_F; j += stride) scal[j] = 0.f;
  for (int j = i; j < Mn; j += stride) cursor[j] = 0;
  int tot = Mn * 64;
  for (int j = i; j < tot; j += stride)
    D[j] = (((j >> 3) & 7) == (j & 7)) ? 1.f : 0.f;
}

__global__ void k_deg(const int* __restrict__ src, const int* __restrict__ dst,
                      int* __restrict__ cnt, int E){
  int i = blockIdx.x * blockDim.x + threadIdx.x;
  int stride = gridDim.x * blockDim.x;
  for (int e = i; e < E; e += stride){
    atomicAdd(&cnt[src[e]], 1);
    atomicAdd(&cnt[dst[e]], 1);
  }
}

// exclusive scan of degrees -> rowptr; cursor = rowptr
__global__ void k_scan(int* __restrict__ cnt, int* __restrict__ rowptr,
                       int* __restrict__ cursor, int Mn, int tot){
  __shared__ int sm[1024];
  const int T = 1024;
  int t = threadIdx.x;
  int chunk = (Mn + T - 1) / T;
  int lo = t * chunk, hi = lo + chunk; if (hi > Mn) hi = Mn;
  int s = 0;
  for (int i = lo; i < hi; ++i) s += cnt[i];
  sm[t] = s;
  __syncthreads();
  for (int o = 1; o < T; o <<= 1){
    int v = (t >= o) ? sm[t - o] : 0;
    __syncthreads();
    sm[t] += v;
    __syncthreads();
  }
  int base = (t == 0) ? 0 : sm[t - 1];
  for (int i = lo; i < hi; ++i){
    int c = cnt[i];
    rowptr[i] = base;
    cursor[i] = base;
    base += c;
  }
  if (t == T - 1) rowptr[Mn] = tot;
}

// fill CSR neighbor slots: col[slot]=partner, es[slot]=(e<<1)|side
__global__ void k_fill(const int* __restrict__ src, const int* __restrict__ dst,
                       int* __restrict__ cursor, int* __restrict__ col,
                       int* __restrict__ es, int E){
  int i = blockIdx.x * blockDim.x + threadIdx.x;
  int stride = gridDim.x * blockDim.x;
  for (int e = i; e < E; e += stride){
    int s = src[e], t = dst[e];
    int ps = atomicAdd(&cursor[s], 1);
    col[ps] = t; es[ps] = (e << 1);
    int pt = atomicAdd(&cursor[t], 1);
    col[pt] = s; es[pt] = (e << 1) | 1;
  }
}

// FUSED edge build (round-3 proven 368us): wave per edge, lane l=(d1,d2).
// M[e] = Rs^T Rd (NT store); D[src] += LAM*Rs^T Rs; D[dst] += LAM*Rd^T Rd.
__global__ void k_edgeM(const float* __restrict__ Rs, const float* __restrict__ Rd,
                        const int* __restrict__ src, const int* __restrict__ dst,
                        float* __restrict__ Mb, float* __restrict__ D, int E){
  int g  = blockIdx.x * blockDim.x + threadIdx.x;
  int wv = g >> 6, l = g & 63;
  int nw = (gridDim.x * blockDim.x) >> 6;
  int d1 = l >> 3, d2 = l & 7;
  for (int e = wv; e < E; e += nw){
    float rs = Rs[(size_t)e * 64 + l];
    float rd = Rd[(size_t)e * 64 + l];
    float As = 0.f, Ad = 0.f, Mm = 0.f;
    #pragma unroll
    for (int a = 0; a < 8; ++a){
      float s1 = __shfl(rs, a * 8 + d1, 64);
      float s2 = __shfl(rs, a * 8 + d2, 64);
      float t1 = __shfl(rd, a * 8 + d1, 64);
      float t2 = __shfl(rd, a * 8 + d2, 64);
      As += s1 * s2;
      Ad += t1 * t2;
      Mm += s1 * t2;
    }
    __builtin_nontemporal_store(Mm, &Mb[(size_t)e * 64 + l]);
    int s = src[e], t = dst[e];
    atomicAdd(&D[(size_t)s * 64 + l], LAM * As);
    atomicAdd(&D[(size_t)t * 64 + l], LAM * Ad);
  }
}

// wave per node. Single-LDS-buffer + register-prefetch M-form matvec
// (round-8 structure, proven 184us). M gathers are NONTEMPORAL (M has zero
// reuse within a dispatch; keep p L2-resident). LDS rows padded to 68 floats.
// No __syncthreads: each wave touches only its own LDS slice.
__global__ void k_mv(const float* __restrict__ Mb, const float* __restrict__ Dd,
                     const int* __restrict__ rowptr, const int* __restrict__ col,
                     const int* __restrict__ es, const float* __restrict__ p,
                     float* __restrict__ out, float* __restrict__ scal, int Mn){
  if (*(const int*)(scal + S_FLAG)) return;
  __shared__ float pbuf[4][8][68];
  __shared__ float mbuf[4][8][68];
  __shared__ int   cbuf[4][128];
  __shared__ int   ebuf[4][128];
  int g = blockIdx.x * blockDim.x + threadIdx.x;
  int v = g >> 6;
  if (v >= Mn) return;
  int w  = threadIdx.x >> 6;
  int l  = g & 63;
  int hi = l >> 3, lo = l & 7;
  int k8 = lo * 8;          // phase-A segment offset / phase-B row offset (dd*8)
  int b8 = hi * 8;          // phase-B batch offset
  int j0 = rowptr[v];
  int rowlen = rowptr[v + 1] - j0;

  // stage col/es for this wave's row (wave-synchronous LDS, no barrier needed)
  for (int jj = l; jj < rowlen && jj < 128; jj += 64){
    cbuf[w][jj] = col[j0 + jj];
    ebuf[w][jj] = es[j0 + jj];
  }

  int nch = (rowlen + 7) >> 3;

  auto gaddr = [&](int n, int& c, int& e){
    int jj = n * 8 + hi;
    c = v; e = 0;
    if (jj < rowlen){
      if (jj < 128){ c = cbuf[w][jj]; e = ebuf[w][jj] >> 1; }
      else         { c = col[j0 + jj]; e = es[j0 + jj] >> 1; }
    }
  };

  // acc = D_v p_v   (D row dd=lo; p row b=hi)
  const f4* pv4 = (const f4*)(p + (size_t)v * 64 + b8);
  f4 pv0 = pv4[0], pv1 = pv4[1];
  const f4* dr4 = (const f4*)(Dd + (size_t)v * 64 + k8);
  float acc = dot8v(dr4[0], dr4[1], pv0, pv1);

  f4 gp0, gp1, gm0, gm1;
  if (nch > 0){
    int c, e; gaddr(0, c, e);
    const float* pc = p + (size_t)c * 64 + k8;
    gp0 = *(const f4*)pc; gp1 = *(const f4*)(pc + 4);
    const f4* mc = (const f4*)(Mb + (size_t)e * 64 + k8);
    gm0 = __builtin_nontemporal_load(mc);
    gm1 = __builtin_nontemporal_load(mc + 1);
  }

  for (int n = 0; n < nch; ++n){
    // commit prefetched chunk to LDS (in-order DS: after prior chunk's reads)
    float* dp = &pbuf[w][hi][k8];
    *(f4*)dp = gp0; *(f4*)(dp + 4) = gp1;
    float* dm = &mbuf[w][hi][k8];
    *(f4*)dm = gm0; *(f4*)(dm + 4) = gm1;
    // issue next chunk's gathers (latency hides under this chunk's compute)
    bool more = (n + 1 < nch);
    if (more){
      int c, e; gaddr(n + 1, c, e);
      const float* pc = p + (size_t)c * 64 + k8;
      gp0 = *(const f4*)pc; gp1 = *(const f4*)(pc + 4);
      const f4* mc = (const f4*)(Mb + (size_t)e * 64 + k8);
      gm0 = __builtin_nontemporal_load(mc);
      gm1 = __builtin_nontemporal_load(mc + 1);
    }
    int jb = n * 8;
    int lim = rowlen - jb;
    if (lim >= 8){
      #pragma unroll
      for (int q = 0; q < 8; ++q){
        int jj = jb + q;                                       // wave-uniform
        int sd = ((jj < 128) ? ebuf[w][jj] : es[j0 + jj]) & 1;
        const float* pr = &pbuf[w][q][b8];
        f4 q0 = *(const f4*)pr, q1 = *(const f4*)(pr + 4);
        const float* mc = &mbuf[w][q][0];
        if (!sd){
          f4 m0 = *(const f4*)(mc + k8);
          f4 m1 = *(const f4*)(mc + k8 + 4);
          acc -= LAM * dot8v(m0, m1, q0, q1);
        } else {
          acc -= LAM * ( mc[lo]      * q0[0] + mc[lo +  8] * q0[1]
                       + mc[lo + 16] * q0[2] + mc[lo + 24] * q0[3]
                       + mc[lo + 32] * q1[0] + mc[lo + 40] * q1[1]
                       + mc[lo + 48] * q1[2] + mc[lo + 56] * q1[3]);
        }
      }
    } else {
      #pragma unroll
      for (int q = 0; q < 8; ++q){
        if (q < lim){
          int jj = jb + q;
          int sd = ((jj < 128) ? ebuf[w][jj] : es[j0 + jj]) & 1;
          const float* pr = &pbuf[w][q][b8];
          f4 q0 = *(const f4*)pr, q1 = *(const f4*)(pr + 4);
          const float* mc = &mbuf[w][q][0];
          if (!sd){
            f4 m0 = *(const f4*)(mc + k8);
            f4 m1 = *(const f4*)(mc + k8 + 4);
            acc -= LAM * dot8v(m0, m1, q0, q1);
          } else {
            acc -= LAM * ( mc[lo]      * q0[0] + mc[lo +  8] * q0[1]
                         + mc[lo + 16] * q0[2] + mc[lo + 24] * q0[3]
                         + mc[lo + 32] * q1[0] + mc[lo + 40] * q1[1]
                         + mc[lo + 48] * q1[2] + mc[lo + 56] * q1[3]);
          }
        }
      }
    }
  }
  out[(size_t)v * 64 + l] = acc;
  // fused p.Ap partial: p element at (v, hi*8+lo) from pv regs
  float pself = (lo & 4) ? ((lo & 2) ? ((lo & 1) ? pv1[3] : pv1[2])
                                     : ((lo & 1) ? pv1[1] : pv1[0]))
                         : ((lo & 2) ? ((lo & 1) ? pv0[3] : pv0[2])
                                     : ((lo & 1) ? pv0[1] : pv0[0]));
  float part = pself * acc;
  part += __shfl_xor(part, 1, 64);
  part += __shfl_xor(part, 2, 64);
  part += __shfl_xor(part, 4, 64);
  if (lo == 0)
    atomicAdd(&scal[S_PAP + hi * 256 + (blockIdx.x & 255)], part);
}

// c0 (batch-major) -> node-major buffer
__global__ void k_perm(const float* __restrict__ c0, float* __restrict__ xp, int Mn){
  int i = blockIdx.x * blockDim.x + threadIdx.x;
  int n4 = Mn * 16;
  if (i >= n4) return;
  int v = i >> 4, rem = i & 15, b = rem >> 1, half = rem & 1;
  f4 cv = *(const f4*)(c0 + ((size_t)b * Mn + v) * 8 + half * 4);
  ((f4*)xp)[i] = cv;
}

// r = c0p - Ap; p = r (in place over c0p); x (batch-major, d_out) = c0
__global__ void k_init_nm(float* __restrict__ p, const float* __restrict__ Ap,
                          float* __restrict__ r, float* __restrict__ x_bm,
                          float* __restrict__ scal, int n4tot, int Mn){
  int i = blockIdx.x * blockDim.x + threadIdx.x;
  int l = threadIdx.x & 63;
  float part = 0.f;
  if (i < n4tot){
    f4 cv = ((const f4*)p)[i];
    f4 av = ((const f4*)Ap)[i];
    f4 rv = cv - av;
    ((f4*)r)[i] = rv;
    ((f4*)p)[i] = rv;
    int v = i >> 4, rem = i & 15, b = rem >> 1, half = rem & 1;
    ((f4*)x_bm)[((size_t)b * Mn + v) * 2 + half] = cv;
    part = rv[0]*rv[0] + rv[1]*rv[1] + rv[2]*rv[2] + rv[3]*rv[3];
  }
  part += __shfl_xor(part, 1, 64);
  part += __shfl_xor(part, 16, 64);
  part += __shfl_xor(part, 32, 64);
  if ((l & 49) == 0)
    atomicAdd(&scal[S_RS + ((l >> 1) & 7) * 256 + (blockIdx.x & 255)], part);
}

// once: RSOLD[b] = sum(S_RS); zero both slot arrays
__global__ void k_s0(float* __restrict__ scal){
  __shared__ float sm[256];
  int t = threadIdx.x;
  int b = t >> 5, k0 = t & 31;
  float s = 0.f;
  #pragma unroll
  for (int i = 0; i < 8; ++i) s += scal[S_RS + b * 256 + k0 + i * 32];
  sm[t] = s;
  __syncthreads();
  if (t < 8){
    float tot = 0.f;
    #pragma unroll
    for (int i = 0; i < 32; ++i) tot += sm[t * 32 + i];
    scal[S_RSOLD + t] = tot;
  }
  __syncthreads();
  for (int i = t; i < 4096; i += 256) scal[S_PAP + i] = 0.f;
}

// x(batch-major) += a p; r -= a Ap; accumulate rnew.rnew
// alpha computed in-block from S_PAP slots (fused)
__global__ void k_upd_nm(float* __restrict__ x_bm, float* __restrict__ r,
                         const float* __restrict__ p, const float* __restrict__ Ap,
                         float* __restrict__ scal, int n4tot, int Mn){
  if (*(const int*)(scal + S_FLAG)) return;
  __shared__ float sal[8];
  int t = threadIdx.x;
  if (t < 8){
    float s = 0.f;
    const float* pp = scal + S_PAP + t * 256;
    #pragma unroll 4
    for (int k = 0; k < 256; ++k) s += pp[k];
    sal[t] = scal[S_RSOLD + t] / (s + 1e-12f);
  }
  __syncthreads();
  int i = blockIdx.x * blockDim.x + t;
  int l = t & 63;
  float part = 0.f;
  if (i < n4tot){
    int v = i >> 4, rem = i & 15, b = rem >> 1, half = rem & 1;
    float al = sal[b];
    size_t xi = ((size_t)b * Mn + v) * 2 + half;
    f4 pv = ((const f4*)p)[i];
    f4 av = ((const f4*)Ap)[i];
    f4 xv = ((f4*)x_bm)[xi];
    f4 rv = ((f4*)r)[i];
    xv += al * pv;
    rv -= al * av;
    ((f4*)x_bm)[xi] = xv;
    ((f4*)r)[i] = rv;
    part = rv[0]*rv[0] + rv[1]*rv[1] + rv[2]*rv[2] + rv[3]*rv[3];
  }
  part += __shfl_xor(part, 1, 64);
  part += __shfl_xor(part, 16, 64);
  part += __shfl_xor(part, 32, 64);
  if ((l & 49) == 0)
    atomicAdd(&scal[S_RS + ((l >> 1) & 7) * 256 + (blockIdx.x & 255)], part);
}

// rsnew from S_RS; conv flag; BETA/RSOLD; zero slot arrays
__global__ void k_s2(float* __restrict__ scal){
  if (*(const int*)(scal + S_FLAG)) return;
  __shared__ float sm[256];
  __shared__ float rsn[8];
  int t = threadIdx.x;
  int b = t >> 5, k0 = t & 31;
  float s = 0.f;
  #pragma unroll
  for (int i = 0; i < 8; ++i) s += scal[S_RS + b * 256 + k0 + i * 32];
  sm[t] = s;
  __syncthreads();
  if (t < 8){
    float tot = 0.f;
    #pragma unroll
    for (int i = 0; i < 32; ++i) tot += sm[t * 32 + i];
    rsn[t] = tot;
  }
  __syncthreads();
  if (t == 0){
    float ssum = 0.f;
    for (int bb = 0; bb < 8; ++bb) ssum += rsn[bb];
    if (sqrtf(ssum / 8.0f) < TOL){
      *(int*)(scal + S_FLAG) = 1;   // freeze
    } else {
      for (int bb = 0; bb < 8; ++bb){
        scal[S_BETA + bb]  = rsn[bb] / (scal[S_RSOLD + bb] + 1e-12f);
        scal[S_RSOLD + bb] = rsn[bb];
      }
    }
  }
  __syncthreads();
  for (int i = t; i < 4096; i += 256) scal[S_PAP + i] = 0.f;
}

__global__ void k_pupd_nm(const float* __restrict__ r, float* __restrict__ p,
                          const float* __restrict__ scal, int n4tot){
  if (*(const int*)(scal + S_FLAG)) return;
  int i = blockIdx.x * blockDim.x + threadIdx.x;
  if (i >= n4tot) return;
  int b = (i >> 1) & 7;
  float be = scal[S_BETA + b];
  f4 rv = ((const f4*)r)[i];
  f4 pv = ((f4*)p)[i];
  pv = rv + be * pv;
  ((f4*)p)[i] = pv;
}

// ---------------- minimal fallback tier (batch-major, R-direct) ----------------
#define OS_RSOLD 0
#define OS_PAP   8
#define OS_RSNEW 16
#define OS_ALPHA 24
#define OS_BETA  32
#define OS_FLAG  40

__device__ __forceinline__ float blk_reduce_256(float v){
  __shared__ float sm[4];
  #pragma unroll
  for (int o = 32; o > 0; o >>= 1) v += __shfl_down(v, o, 64);
  int lane = threadIdx.x & 63, w = threadIdx.x >> 6;
  if (lane == 0) sm[w] = v;
  __syncthreads();
  return (threadIdx.x == 0) ? (sm[0] + sm[1] + sm[2] + sm[3]) : 0.f;
}

__global__ void k_setup_fb(float* scal){
  int i = blockIdx.x * blockDim.x + threadIdx.x;
  if (i < 64) scal[i] = 0.f;
}

__global__ void k_apinit(const float* __restrict__ in, float* __restrict__ out,
                         int n4tot, const int* __restrict__ flag){
  if (*flag) return;
  int j = blockIdx.x * blockDim.x + threadIdx.x;
  if (j < n4tot) ((f4*)out)[j] = ((const f4*)in)[j];
}

__global__ void k_mv_edge_fb(const float* __restrict__ Rs, const float* __restrict__ Rd,
                             const int* __restrict__ src, const int* __restrict__ dst,
                             const float* __restrict__ in, float* __restrict__ out,
                             int Mn, int E, const int* __restrict__ flag){
  if (*flag) return;
  int g  = blockIdx.x * blockDim.x + threadIdx.x;
  int wv = g >> 6, l = g & 63;
  int nw = (gridDim.x * blockDim.x) >> 6;
  int b = l >> 3, q = l & 7;
  for (int e = wv; e < E; e += nw){
    int s = src[e], t = dst[e];
    const f4* rs4 = (const f4*)(Rs + (size_t)e * 64 + q * 8);
    const f4* rd4 = (const f4*)(Rd + (size_t)e * 64 + q * 8);
    const f4* ps4 = (const f4*)(in + ((size_t)b * Mn + s) * 8);
    const f4* pd4 = (const f4*)(in + ((size_t)b * Mn + t) * 8);
    f4 ra0 = rs4[0], ra1 = rs4[1], pa0 = ps4[0], pa1 = ps4[1];
    f4 rb0 = rd4[0], rb1 = rd4[1], pb0 = pd4[0], pb1 = pd4[1];
    float re = dot8v(ra0, ra1, pa0, pa1) - dot8v(rb0, rb1, pb0, pb1);
    float cs = 0.f, cd = 0.f;
    #pragma unroll
    for (int a = 0; a < 8; ++a){
      float rea = __shfl(re, b * 8 + a, 64);
      cs += Rs[(size_t)e * 64 + a * 8 + q] * rea;
      cd += Rd[(size_t)e * 64 + a * 8 + q] * rea;
    }
    atomicAdd(&out[((size_t)b * Mn + s) * 8 + q],  LAM * cs);
    atomicAdd(&out[((size_t)b * Mn + t) * 8 + q], -LAM * cd);
  }
}

__global__ void k_init_o(const float* __restrict__ c0, const float* __restrict__ Ap,
                         float* __restrict__ x, float* __restrict__ r, float* __restrict__ p,
                         float* scal, int n4){
  int b = blockIdx.y;
  size_t base = (size_t)b * n4;
  int j = blockIdx.x * blockDim.x + threadIdx.x;
  float part = 0.f;
  if (j < n4){
    f4 cv = ((const f4*)c0)[base + j];
    f4 av = ((const f4*)Ap)[base + j];
    f4 rv = cv - av;
    ((f4*)x)[base + j] = cv;
    ((f4*)r)[base + j] = rv;
    ((f4*)p)[base + j] = rv;
    part = rv[0]*rv[0] + rv[1]*rv[1] + rv[2]*rv[2] + rv[3]*rv[3];
  }
  float tot = blk_reduce_256(part);
  if (threadIdx.x == 0) atomicAdd(&scal[OS_RSOLD + b], tot);
}

__global__ void k_dot_o(const float* __restrict__ p, const float* __restrict__ Ap,
                        float* scal, int n4){
  const int* flag = (const int*)(scal + OS_FLAG);
  if (*flag) return;
  int b = blockIdx.y;
  size_t base = (size_t)b * n4;
  int j = blockIdx.x * blockDim.x + threadIdx.x;
  float part = 0.f;
  if (j < n4){
    f4 pv = ((const f4*)p)[base + j];
    f4 av = ((const f4*)Ap)[base + j];
    part = pv[0]*av[0] + pv[1]*av[1] + pv[2]*av[2] + pv[3]*av[3];
  }
  float tot = blk_reduce_256(part);
  if (threadIdx.x == 0) atomicAdd(&scal[OS_PAP + b], tot);
}

__global__ void k_s1_o(float* scal){
  const int* flag = (const int*)(scal + OS_FLAG);
  if (*flag) return;
  int t = threadIdx.x;
  if (t < 8){
    scal[OS_ALPHA + t] = scal[OS_RSOLD + t] / (scal[OS_PAP + t] + 1e-12f);
    scal[OS_RSNEW + t] = 0.f;
  }
}

__global__ void k_upd_o(float* __restrict__ x, float* __restrict__ r,
                        const float* __restrict__ p, const float* __restrict__ Ap,
                        float* scal, int n4){
  const int* flag = (const int*)(scal + OS_FLAG);
  if (*flag) return;
  int b = blockIdx.y;
  size_t base = (size_t)b * n4;
  float al = scal[OS_ALPHA + b];
  int j = blockIdx.x * blockDim.x + threadIdx.x;
  float part = 0.f;
  if (j < n4){
    f4 pv = ((const f4*)p)[base + j];
    f4 av = ((const f4*)Ap)[base + j];
    f4 xv = ((f4*)x)[base + j];
    f4 rv = ((f4*)r)[base + j];
    xv += al * pv;
    rv -= al * av;
    ((f4*)x)[base + j] = xv;
    ((f4*)r)[base + j] = rv;
    part = rv[0]*rv[0] + rv[1]*rv[1] + rv[2]*rv[2] + rv[3]*rv[3];
  }
  float tot = blk_reduce_256(part);
  if (threadIdx.x == 0) atomicAdd(&scal[OS_RSNEW + b], tot);
}

__global__ void k_s2_o(float* scal){
  int* flag = (int*)(scal + OS_FLAG);
  if (*flag) return;
  if (threadIdx.x == 0){
    float ssum = 0.f;
    for (int bb = 0; bb < 8; ++bb) ssum += scal[OS_RSNEW + bb];
    if (sqrtf(ssum / 8.0f) < TOL){
      *flag = 1;
    } else {
      for (int bb = 0; bb < 8; ++bb){
        scal[OS_BETA + bb]  = scal[OS_RSNEW + bb] / (scal[OS_RSOLD + bb] + 1e-12f);
        scal[OS_RSOLD + bb] = scal[OS_RSNEW + bb];
        scal[OS_PAP + bb]   = 0.f;
      }
    }
  }
}

__global__ void k_pupd_o(const float* __restrict__ r, float* __restrict__ p,
                         float* scal, int n4){
  const int* flag = (const int*)(scal + OS_FLAG);
  if (*flag) return;
  int b = blockIdx.y;
  size_t base = (size_t)b * n4;
  float be = scal[OS_BETA + b];
  int j = blockIdx.x * blockDim.x + threadIdx.x;
  if (j < n4){
    f4 rv = ((const f4*)r)[base + j];
    f4 pv = ((f4*)p)[base + j];
    pv = rv + be * pv;
    ((f4*)p)[base + j] = pv;
  }
}

// ---------------- launch ----------------
extern "C" void kernel_launch(void* const* d_in, const int* in_sizes, int n_in,
                              void* d_out, int out_size, void* d_ws, size_t ws_size,
                              hipStream_t stream){
  const float* c0  = (const float*)d_in[0];
  const int*   src = (const int*)d_in[1];
  const int*   dst = (const int*)d_in[2];
  const float* Rs  = (const float*)d_in[3];
  const float* Rd  = (const float*)d_in[4];

  int N  = in_sizes[0];          // B*Mn*8 floats, B=8, d=8
  int Mn = N / 64;
  int E  = in_sizes[1];
  int n4tot = N / 4;
  int twoE = 2 * E;

  float* ws = (float*)d_ws;
  size_t off = 0;
  float* r    = ws + off;  off += N;
  float* p    = ws + off;  off += N;
  float* Ap   = ws + off;  off += N;
  float* scal = ws + off;  off += SCAL_F;
  float* Dd   = ws + off;  off += (size_t)Mn * 64;
  int* rowptr = (int*)(ws + off);  off += (size_t)((Mn + 1 + 3) & ~3);
  int* cursor = (int*)(ws + off);  off += (size_t)((Mn + 3) & ~3);
  int* colA   = (int*)(ws + off);  off += (size_t)twoE;
  int* esA    = (int*)(ws + off);  off += (size_t)twoE;
  float* Mb   = ws + off;  off += (size_t)E * 64;
  size_t need_main = off * 4;

  int nb_vec  = (n4tot + 255) / 256;
  int nb_node = (Mn * 64 + 255) / 256;

  if (ws_size >= need_main){
    k_setup_nm<<<2048, 256, 0, stream>>>(Dd, scal, cursor, Mn);
    k_deg  <<<1024, 256, 0, stream>>>(src, dst, cursor, E);
    k_scan <<<1, 1024, 0, stream>>>(cursor, rowptr, cursor, Mn, twoE);
    k_fill <<<1024, 256, 0, stream>>>(src, dst, cursor, colA, esA, E);
    k_edgeM<<<4096, 256, 0, stream>>>(Rs, Rd, src, dst, Mb, Dd, E);

    float* x_bm = (float*)d_out;
    k_perm<<<nb_vec, 256, 0, stream>>>(c0, p, Mn);   // p := c0 (node-major)
    k_mv<<<nb_node, 256, 0, stream>>>(Mb, Dd, rowptr, colA, esA, p, Ap, scal, Mn);
    k_init_nm<<<nb_vec, 256, 0, stream>>>(p, Ap, r, x_bm, scal, n4tot, Mn);
    k_s0<<<1, 256, 0, stream>>>(scal);

    for (int it = 0; it < NIT; ++it){
      k_mv<<<nb_node, 256, 0, stream>>>(Mb, Dd, rowptr, colA, esA, p, Ap, scal, Mn);
      k_upd_nm<<<nb_vec, 256, 0, stream>>>(x_bm, r, p, Ap, scal, n4tot, Mn);
      k_s2<<<1, 256, 0, stream>>>(scal);
      k_pupd_nm<<<nb_vec, 256, 0, stream>>>(r, p, scal, n4tot);
    }
  } else {
    // fallback: batch-major R-direct (needs 3N+64 floats)
    float* fr    = ws;
    float* fp    = fr + N;
    float* fAp   = fp + N;
    float* fscal = fAp + N;
    const int* flagp = (const int*)(fscal + OS_FLAG);
    int n4 = Mn * 2;
    dim3 vgrid((n4 + 255) / 256, 8);
    int cb = (n4tot + 255) / 256;
    float* x = (float*)d_out;

    k_setup_fb<<<1, 64, 0, stream>>>(fscal);
    k_apinit<<<cb, 256, 0, stream>>>(c0, fAp, n4tot, flagp);
    k_mv_edge_fb<<<2048, 256, 0, stream>>>(Rs, Rd, src, dst, c0, fAp, Mn, E, flagp);
    k_init_o<<<vgrid, 256, 0, stream>>>(c0, fAp, x, fr, fp, fscal, n4);
    for (int it = 0; it < NIT; ++it){
      k_apinit<<<cb, 256, 0, stream>>>(fp, fAp, n4tot, flagp);
      k_mv_edge_fb<<<2048, 256, 0, stream>>>(Rs, Rd, src, dst, fp, fAp, Mn, E, flagp);
      k_dot_o<<<vgrid, 256, 0, stream>>>(fp, fAp, fscal, n4);
      k_s1_o<<<1, 64, 0, stream>>>(fscal);
      k_upd_o<<<vgrid, 256, 0, stream>>>(x, fr, fp, fAp, fscal, n4);
      k_s2_o<<<1, 64, 0, stream>>>(fscal);
      k_pupd_o<<<vgrid, 256, 0, stream>>>(fr, fp, fscal, n4);
    }
  }
}

// Round 12
// 4989.535 us; speedup vs baseline: 2.1048x; 1.0920x over previous
//
#include <hip/hip_runtime.h>
#include <math.h>

constexpr float LAM = 1.0f;
constexpr int   NIT = 20;
constexpr float TOL = 1e-6f;

typedef float f4 __attribute__((ext_vector_type(4)));

// ---------------- scal layout (floats) ----------------
#define S_RSOLD 0
#define S_ALPHA 8
#define S_BETA  16
#define S_FLAG  24        // int alias
#define S_PAP   32        // [8][256] partial slots for p.Ap
#define S_RS    (32+2048) // [8][256] partial slots for r.r
#define SCAL_F  (32+4096)

__device__ __forceinline__ float dot8v(f4 a0, f4 a1, f4 b0, f4 b1){
  return a0[0]*b0[0] + a0[1]*b0[1] + a0[2]*b0[2] + a0[3]*b0[3]
       + a1[0]*b1[0] + a1[1]*b1[1] + a1[2]*b1[2] + a1[3]*b1[3];
}

// zero scal, zero cursor, D := I
__global__ void k_setup_nm(float* __restrict__ D, float* __restrict__ scal,
                           int* __restrict__ cursor, int Mn){
  int i = blockIdx.x * blockDim.x + threadIdx.x;
  int stride = gridDim.x * blockDim.x;
  for (int j = i; j < SCAL_F; j += stride) scal[j] = 0.f;
  for (int j = i; j < Mn; j += stride) cursor[j] = 0;
  int tot = Mn * 64;
  for (int j = i; j < tot; j += stride)
    D[j] = (((j >> 3) & 7) == (j & 7)) ? 1.f : 0.f;
}

__global__ void k_deg(const int* __restrict__ src, const int* __restrict__ dst,
                      int* __restrict__ cnt, int E){
  int i = blockIdx.x * blockDim.x + threadIdx.x;
  int stride = gridDim.x * blockDim.x;
  for (int e = i; e < E; e += stride){
    atomicAdd(&cnt[src[e]], 1);
    atomicAdd(&cnt[dst[e]], 1);
  }
}

// exclusive scan of degrees -> rowptr; cursor = rowptr
__global__ void k_scan(int* __restrict__ cnt, int* __restrict__ rowptr,
                       int* __restrict__ cursor, int Mn, int tot){
  __shared__ int sm[1024];
  const int T = 1024;
  int t = threadIdx.x;
  int chunk = (Mn + T - 1) / T;
  int lo = t * chunk, hi = lo + chunk; if (hi > Mn) hi = Mn;
  int s = 0;
  for (int i = lo; i < hi; ++i) s += cnt[i];
  sm[t] = s;
  __syncthreads();
  for (int o = 1; o < T; o <<= 1){
    int v = (t >= o) ? sm[t - o] : 0;
    __syncthreads();
    sm[t] += v;
    __syncthreads();
  }
  int base = (t == 0) ? 0 : sm[t - 1];
  for (int i = lo; i < hi; ++i){
    int c = cnt[i];
    rowptr[i] = base;
    cursor[i] = base;
    base += c;
  }
  if (t == T - 1) rowptr[Mn] = tot;
}

// fill CSR neighbor slots: col[slot]=partner, es[slot]=(e<<1)|side
__global__ void k_fill(const int* __restrict__ src, const int* __restrict__ dst,
                       int* __restrict__ cursor, int* __restrict__ col,
                       int* __restrict__ es, int E){
  int i = blockIdx.x * blockDim.x + threadIdx.x;
  int stride = gridDim.x * blockDim.x;
  for (int e = i; e < E; e += stride){
    int s = src[e], t = dst[e];
    int ps = atomicAdd(&cursor[s], 1);
    col[ps] = t; es[ps] = (e << 1);
    int pt = atomicAdd(&cursor[t], 1);
    col[pt] = s; es[pt] = (e << 1) | 1;
  }
}

// FUSED edge build (round-3 proven 368us): wave per edge, lane l=(d1,d2).
// M[e] = Rs^T Rd (plain store -> cache-allocated for k_mv's reads);
// D[src] += LAM*Rs^T Rs; D[dst] += LAM*Rd^T Rd.
__global__ void k_edgeM(const float* __restrict__ Rs, const float* __restrict__ Rd,
                        const int* __restrict__ src, const int* __restrict__ dst,
                        float* __restrict__ Mb, float* __restrict__ D, int E){
  int g  = blockIdx.x * blockDim.x + threadIdx.x;
  int wv = g >> 6, l = g & 63;
  int nw = (gridDim.x * blockDim.x) >> 6;
  int d1 = l >> 3, d2 = l & 7;
  for (int e = wv; e < E; e += nw){
    float rs = Rs[(size_t)e * 64 + l];
    float rd = Rd[(size_t)e * 64 + l];
    float As = 0.f, Ad = 0.f, Mm = 0.f;
    #pragma unroll
    for (int a = 0; a < 8; ++a){
      float s1 = __shfl(rs, a * 8 + d1, 64);
      float s2 = __shfl(rs, a * 8 + d2, 64);
      float t1 = __shfl(rd, a * 8 + d1, 64);
      float t2 = __shfl(rd, a * 8 + d2, 64);
      As += s1 * s2;
      Ad += t1 * t2;
      Mm += s1 * t2;
    }
    Mb[(size_t)e * 64 + l] = Mm;
    int s = src[e], t = dst[e];
    atomicAdd(&D[(size_t)s * 64 + l], LAM * As);
    atomicAdd(&D[(size_t)t * 64 + l], LAM * Ad);
  }
}

// wave per node. Single-LDS-buffer + register-prefetch M-form matvec
// (round-8 structure, proven 184us; plain cached loads — M rows are read
// TWICE per matvec (src side + dst side), keep that L2/L3 reuse).
// LDS rows padded to 68 floats. No __syncthreads: wave-private LDS slices.
__global__ void k_mv(const float* __restrict__ Mb, const float* __restrict__ Dd,
                     const int* __restrict__ rowptr, const int* __restrict__ col,
                     const int* __restrict__ es, const float* __restrict__ p,
                     float* __restrict__ out, float* __restrict__ scal, int Mn){
  if (*(const int*)(scal + S_FLAG)) return;
  __shared__ float pbuf[4][8][68];
  __shared__ float mbuf[4][8][68];
  __shared__ int   cbuf[4][128];
  __shared__ int   ebuf[4][128];
  int g = blockIdx.x * blockDim.x + threadIdx.x;
  int v = g >> 6;
  if (v >= Mn) return;
  int w  = threadIdx.x >> 6;
  int l  = g & 63;
  int hi = l >> 3, lo = l & 7;
  int k8 = lo * 8;          // phase-A segment offset / phase-B row offset (dd*8)
  int b8 = hi * 8;          // phase-B batch offset
  int j0 = rowptr[v];
  int rowlen = rowptr[v + 1] - j0;

  // stage col/es for this wave's row (wave-synchronous LDS, no barrier needed)
  for (int jj = l; jj < rowlen && jj < 128; jj += 64){
    cbuf[w][jj] = col[j0 + jj];
    ebuf[w][jj] = es[j0 + jj];
  }

  int nch = (rowlen + 7) >> 3;

  auto gaddr = [&](int n, int& c, int& e){
    int jj = n * 8 + hi;
    c = v; e = 0;
    if (jj < rowlen){
      if (jj < 128){ c = cbuf[w][jj]; e = ebuf[w][jj] >> 1; }
      else         { c = col[j0 + jj]; e = es[j0 + jj] >> 1; }
    }
  };

  // acc = D_v p_v   (D row dd=lo; p row b=hi)
  const f4* pv4 = (const f4*)(p + (size_t)v * 64 + b8);
  f4 pv0 = pv4[0], pv1 = pv4[1];
  const f4* dr4 = (const f4*)(Dd + (size_t)v * 64 + k8);
  float acc = dot8v(dr4[0], dr4[1], pv0, pv1);

  f4 gp0, gp1, gm0, gm1;
  if (nch > 0){
    int c, e; gaddr(0, c, e);
    const float* pc = p + (size_t)c * 64 + k8;
    gp0 = *(const f4*)pc; gp1 = *(const f4*)(pc + 4);
    const float* mc = Mb + (size_t)e * 64 + k8;
    gm0 = *(const f4*)mc; gm1 = *(const f4*)(mc + 4);
  }

  for (int n = 0; n < nch; ++n){
    // commit prefetched chunk to LDS (in-order DS: after prior chunk's reads)
    float* dp = &pbuf[w][hi][k8];
    *(f4*)dp = gp0; *(f4*)(dp + 4) = gp1;
    float* dm = &mbuf[w][hi][k8];
    *(f4*)dm = gm0; *(f4*)(dm + 4) = gm1;
    // issue next chunk's gathers (latency hides under this chunk's compute)
    bool more = (n + 1 < nch);
    if (more){
      int c, e; gaddr(n + 1, c, e);
      const float* pc = p + (size_t)c * 64 + k8;
      gp0 = *(const f4*)pc; gp1 = *(const f4*)(pc + 4);
      const float* mc = Mb + (size_t)e * 64 + k8;
      gm0 = *(const f4*)mc; gm1 = *(const f4*)(mc + 4);
    }
    int jb = n * 8;
    int lim = rowlen - jb;
    if (lim >= 8){
      #pragma unroll
      for (int q = 0; q < 8; ++q){
        int jj = jb + q;                                       // wave-uniform
        int sd = ((jj < 128) ? ebuf[w][jj] : es[j0 + jj]) & 1;
        const float* pr = &pbuf[w][q][b8];
        f4 q0 = *(const f4*)pr, q1 = *(const f4*)(pr + 4);
        const float* mc = &mbuf[w][q][0];
        if (!sd){
          f4 m0 = *(const f4*)(mc + k8);
          f4 m1 = *(const f4*)(mc + k8 + 4);
          acc -= LAM * dot8v(m0, m1, q0, q1);
        } else {
          acc -= LAM * ( mc[lo]      * q0[0] + mc[lo +  8] * q0[1]
                       + mc[lo + 16] * q0[2] + mc[lo + 24] * q0[3]
                       + mc[lo + 32] * q1[0] + mc[lo + 40] * q1[1]
                       + mc[lo + 48] * q1[2] + mc[lo + 56] * q1[3]);
        }
      }
    } else {
      #pragma unroll
      for (int q = 0; q < 8; ++q){
        if (q < lim){
          int jj = jb + q;
          int sd = ((jj < 128) ? ebuf[w][jj] : es[j0 + jj]) & 1;
          const float* pr = &pbuf[w][q][b8];
          f4 q0 = *(const f4*)pr, q1 = *(const f4*)(pr + 4);
          const float* mc = &mbuf[w][q][0];
          if (!sd){
            f4 m0 = *(const f4*)(mc + k8);
            f4 m1 = *(const f4*)(mc + k8 + 4);
            acc -= LAM * dot8v(m0, m1, q0, q1);
          } else {
            acc -= LAM * ( mc[lo]      * q0[0] + mc[lo +  8] * q0[1]
                         + mc[lo + 16] * q0[2] + mc[lo + 24] * q0[3]
                         + mc[lo + 32] * q1[0] + mc[lo + 40] * q1[1]
                         + mc[lo + 48] * q1[2] + mc[lo + 56] * q1[3]);
          }
        }
      }
    }
  }
  out[(size_t)v * 64 + l] = acc;
  // fused p.Ap partial: p element at (v, hi*8+lo) from pv regs
  float pself = (lo & 4) ? ((lo & 2) ? ((lo & 1) ? pv1[3] : pv1[2])
                                     : ((lo & 1) ? pv1[1] : pv1[0]))
                         : ((lo & 2) ? ((lo & 1) ? pv0[3] : pv0[2])
                                     : ((lo & 1) ? pv0[1] : pv0[0]));
  float part = pself * acc;
  part += __shfl_xor(part, 1, 64);
  part += __shfl_xor(part, 2, 64);
  part += __shfl_xor(part, 4, 64);
  if (lo == 0)
    atomicAdd(&scal[S_PAP + hi * 256 + (blockIdx.x & 255)], part);
}

// c0 (batch-major) -> node-major buffer
__global__ void k_perm(const float* __restrict__ c0, float* __restrict__ xp, int Mn){
  int i = blockIdx.x * blockDim.x + threadIdx.x;
  int n4 = Mn * 16;
  if (i >= n4) return;
  int v = i >> 4, rem = i & 15, b = rem >> 1, half = rem & 1;
  f4 cv = *(const f4*)(c0 + ((size_t)b * Mn + v) * 8 + half * 4);
  ((f4*)xp)[i] = cv;
}

// r = c0p - Ap; p = r (in place over c0p); x (batch-major, d_out) = c0
__global__ void k_init_nm(float* __restrict__ p, const float* __restrict__ Ap,
                          float* __restrict__ r, float* __restrict__ x_bm,
                          float* __restrict__ scal, int n4tot, int Mn){
  int i = blockIdx.x * blockDim.x + threadIdx.x;
  int l = threadIdx.x & 63;
  float part = 0.f;
  if (i < n4tot){
    f4 cv = ((const f4*)p)[i];
    f4 av = ((const f4*)Ap)[i];
    f4 rv = cv - av;
    ((f4*)r)[i] = rv;
    ((f4*)p)[i] = rv;
    int v = i >> 4, rem = i & 15, b = rem >> 1, half = rem & 1;
    ((f4*)x_bm)[((size_t)b * Mn + v) * 2 + half] = cv;
    part = rv[0]*rv[0] + rv[1]*rv[1] + rv[2]*rv[2] + rv[3]*rv[3];
  }
  part += __shfl_xor(part, 1, 64);
  part += __shfl_xor(part, 16, 64);
  part += __shfl_xor(part, 32, 64);
  if ((l & 49) == 0)
    atomicAdd(&scal[S_RS + ((l >> 1) & 7) * 256 + (blockIdx.x & 255)], part);
}

// once: RSOLD[b] = sum(S_RS); zero both slot arrays
__global__ void k_s0(float* __restrict__ scal){
  __shared__ float sm[256];
  int t = threadIdx.x;
  int b = t >> 5, k0 = t & 31;
  float s = 0.f;
  #pragma unroll
  for (int i = 0; i < 8; ++i) s += scal[S_RS + b * 256 + k0 + i * 32];
  sm[t] = s;
  __syncthreads();
  if (t < 8){
    float tot = 0.f;
    #pragma unroll
    for (int i = 0; i < 32; ++i) tot += sm[t * 32 + i];
    scal[S_RSOLD + t] = tot;
  }
  __syncthreads();
  for (int i = t; i < 4096; i += 256) scal[S_PAP + i] = 0.f;
}

// x(batch-major) += a p; r -= a Ap; accumulate rnew.rnew
// alpha computed in-block from S_PAP slots (fused)
__global__ void k_upd_nm(float* __restrict__ x_bm, float* __restrict__ r,
                         const float* __restrict__ p, const float* __restrict__ Ap,
                         float* __restrict__ scal, int n4tot, int Mn){
  if (*(const int*)(scal + S_FLAG)) return;
  __shared__ float sal[8];
  int t = threadIdx.x;
  if (t < 8){
    float s = 0.f;
    const float* pp = scal + S_PAP + t * 256;
    #pragma unroll 4
    for (int k = 0; k < 256; ++k) s += pp[k];
    sal[t] = scal[S_RSOLD + t] / (s + 1e-12f);
  }
  __syncthreads();
  int i = blockIdx.x * blockDim.x + t;
  int l = t & 63;
  float part = 0.f;
  if (i < n4tot){
    int v = i >> 4, rem = i & 15, b = rem >> 1, half = rem & 1;
    float al = sal[b];
    size_t xi = ((size_t)b * Mn + v) * 2 + half;
    f4 pv = ((const f4*)p)[i];
    f4 av = ((const f4*)Ap)[i];
    f4 xv = ((f4*)x_bm)[xi];
    f4 rv = ((f4*)r)[i];
    xv += al * pv;
    rv -= al * av;
    ((f4*)x_bm)[xi] = xv;
    ((f4*)r)[i] = rv;
    part = rv[0]*rv[0] + rv[1]*rv[1] + rv[2]*rv[2] + rv[3]*rv[3];
  }
  part += __shfl_xor(part, 1, 64);
  part += __shfl_xor(part, 16, 64);
  part += __shfl_xor(part, 32, 64);
  if ((l & 49) == 0)
    atomicAdd(&scal[S_RS + ((l >> 1) & 7) * 256 + (blockIdx.x & 255)], part);
}

// rsnew from S_RS; conv flag; BETA/RSOLD; zero slot arrays
__global__ void k_s2(float* __restrict__ scal){
  if (*(const int*)(scal + S_FLAG)) return;
  __shared__ float sm[256];
  __shared__ float rsn[8];
  int t = threadIdx.x;
  int b = t >> 5, k0 = t & 31;
  float s = 0.f;
  #pragma unroll
  for (int i = 0; i < 8; ++i) s += scal[S_RS + b * 256 + k0 + i * 32];
  sm[t] = s;
  __syncthreads();
  if (t < 8){
    float tot = 0.f;
    #pragma unroll
    for (int i = 0; i < 32; ++i) tot += sm[t * 32 + i];
    rsn[t] = tot;
  }
  __syncthreads();
  if (t == 0){
    float ssum = 0.f;
    for (int bb = 0; bb < 8; ++bb) ssum += rsn[bb];
    if (sqrtf(ssum / 8.0f) < TOL){
      *(int*)(scal + S_FLAG) = 1;   // freeze
    } else {
      for (int bb = 0; bb < 8; ++bb){
        scal[S_BETA + bb]  = rsn[bb] / (scal[S_RSOLD + bb] + 1e-12f);
        scal[S_RSOLD + bb] = rsn[bb];
      }
    }
  }
  __syncthreads();
  for (int i = t; i < 4096; i += 256) scal[S_PAP + i] = 0.f;
}

__global__ void k_pupd_nm(const float* __restrict__ r, float* __restrict__ p,
                          const float* __restrict__ scal, int n4tot){
  if (*(const int*)(scal + S_FLAG)) return;
  int i = blockIdx.x * blockDim.x + threadIdx.x;
  if (i >= n4tot) return;
  int b = (i >> 1) & 7;
  float be = scal[S_BETA + b];
  f4 rv = ((const f4*)r)[i];
  f4 pv = ((f4*)p)[i];
  pv = rv + be * pv;
  ((f4*)p)[i] = pv;
}

// ---------------- minimal fallback tier (batch-major, R-direct) ----------------
#define OS_RSOLD 0
#define OS_PAP   8
#define OS_RSNEW 16
#define OS_ALPHA 24
#define OS_BETA  32
#define OS_FLAG  40

__device__ __forceinline__ float blk_reduce_256(float v){
  __shared__ float sm[4];
  #pragma unroll
  for (int o = 32; o > 0; o >>= 1) v += __shfl_down(v, o, 64);
  int lane = threadIdx.x & 63, w = threadIdx.x >> 6;
  if (lane == 0) sm[w] = v;
  __syncthreads();
  return (threadIdx.x == 0) ? (sm[0] + sm[1] + sm[2] + sm[3]) : 0.f;
}

__global__ void k_setup_fb(float* scal){
  int i = blockIdx.x * blockDim.x + threadIdx.x;
  if (i < 64) scal[i] = 0.f;
}

__global__ void k_apinit(const float* __restrict__ in, float* __restrict__ out,
                         int n4tot, const int* __restrict__ flag){
  if (*flag) return;
  int j = blockIdx.x * blockDim.x + threadIdx.x;
  if (j < n4tot) ((f4*)out)[j] = ((const f4*)in)[j];
}

__global__ void k_mv_edge_fb(const float* __restrict__ Rs, const float* __restrict__ Rd,
                             const int* __restrict__ src, const int* __restrict__ dst,
                             const float* __restrict__ in, float* __restrict__ out,
                             int Mn, int E, const int* __restrict__ flag){
  if (*flag) return;
  int g  = blockIdx.x * blockDim.x + threadIdx.x;
  int wv = g >> 6, l = g & 63;
  int nw = (gridDim.x * blockDim.x) >> 6;
  int b = l >> 3, q = l & 7;
  for (int e = wv; e < E; e += nw){
    int s = src[e], t = dst[e];
    const f4* rs4 = (const f4*)(Rs + (size_t)e * 64 + q * 8);
    const f4* rd4 = (const f4*)(Rd + (size_t)e * 64 + q * 8);
    const f4* ps4 = (const f4*)(in + ((size_t)b * Mn + s) * 8);
    const f4* pd4 = (const f4*)(in + ((size_t)b * Mn + t) * 8);
    f4 ra0 = rs4[0], ra1 = rs4[1], pa0 = ps4[0], pa1 = ps4[1];
    f4 rb0 = rd4[0], rb1 = rd4[1], pb0 = pd4[0], pb1 = pd4[1];
    float re = dot8v(ra0, ra1, pa0, pa1) - dot8v(rb0, rb1, pb0, pb1);
    float cs = 0.f, cd = 0.f;
    #pragma unroll
    for (int a = 0; a < 8; ++a){
      float rea = __shfl(re, b * 8 + a, 64);
      cs += Rs[(size_t)e * 64 + a * 8 + q] * rea;
      cd += Rd[(size_t)e * 64 + a * 8 + q] * rea;
    }
    atomicAdd(&out[((size_t)b * Mn + s) * 8 + q],  LAM * cs);
    atomicAdd(&out[((size_t)b * Mn + t) * 8 + q], -LAM * cd);
  }
}

__global__ void k_init_o(const float* __restrict__ c0, const float* __restrict__ Ap,
                         float* __restrict__ x, float* __restrict__ r, float* __restrict__ p,
                         float* scal, int n4){
  int b = blockIdx.y;
  size_t base = (size_t)b * n4;
  int j = blockIdx.x * blockDim.x + threadIdx.x;
  float part = 0.f;
  if (j < n4){
    f4 cv = ((const f4*)c0)[base + j];
    f4 av = ((const f4*)Ap)[base + j];
    f4 rv = cv - av;
    ((f4*)x)[base + j] = cv;
    ((f4*)r)[base + j] = rv;
    ((f4*)p)[base + j] = rv;
    part = rv[0]*rv[0] + rv[1]*rv[1] + rv[2]*rv[2] + rv[3]*rv[3];
  }
  float tot = blk_reduce_256(part);
  if (threadIdx.x == 0) atomicAdd(&scal[OS_RSOLD + b], tot);
}

__global__ void k_dot_o(const float* __restrict__ p, const float* __restrict__ Ap,
                        float* scal, int n4){
  const int* flag = (const int*)(scal + OS_FLAG);
  if (*flag) return;
  int b = blockIdx.y;
  size_t base = (size_t)b * n4;
  int j = blockIdx.x * blockDim.x + threadIdx.x;
  float part = 0.f;
  if (j < n4){
    f4 pv = ((const f4*)p)[base + j];
    f4 av = ((const f4*)Ap)[base + j];
    part = pv[0]*av[0] + pv[1]*av[1] + pv[2]*av[2] + pv[3]*av[3];
  }
  float tot = blk_reduce_256(part);
  if (threadIdx.x == 0) atomicAdd(&scal[OS_PAP + b], tot);
}

__global__ void k_s1_o(float* scal){
  const int* flag = (const int*)(scal + OS_FLAG);
  if (*flag) return;
  int t = threadIdx.x;
  if (t < 8){
    scal[OS_ALPHA + t] = scal[OS_RSOLD + t] / (scal[OS_PAP + t] + 1e-12f);
    scal[OS_RSNEW + t] = 0.f;
  }
}

__global__ void k_upd_o(float* __restrict__ x, float* __restrict__ r,
                        const float* __restrict__ p, const float* __restrict__ Ap,
                        float* scal, int n4){
  const int* flag = (const int*)(scal + OS_FLAG);
  if (*flag) return;
  int b = blockIdx.y;
  size_t base = (size_t)b * n4;
  float al = scal[OS_ALPHA + b];
  int j = blockIdx.x * blockDim.x + threadIdx.x;
  float part = 0.f;
  if (j < n4){
    f4 pv = ((const f4*)p)[base + j];
    f4 av = ((const f4*)Ap)[base + j];
    f4 xv = ((f4*)x)[base + j];
    f4 rv = ((f4*)r)[base + j];
    xv += al * pv;
    rv -= al * av;
    ((f4*)x)[base + j] = xv;
    ((f4*)r)[base + j] = rv;
    part = rv[0]*rv[0] + rv[1]*rv[1] + rv[2]*rv[2] + rv[3]*rv[3];
  }
  float tot = blk_reduce_256(part);
  if (threadIdx.x == 0) atomicAdd(&scal[OS_RSNEW + b], tot);
}

__global__ void k_s2_o(float* scal){
  int* flag = (int*)(scal + OS_FLAG);
  if (*flag) return;
  if (threadIdx.x == 0){
    float ssum = 0.f;
    for (int bb = 0; bb < 8; ++bb) ssum += scal[OS_RSNEW + bb];
    if (sqrtf(ssum / 8.0f) < TOL){
      *flag = 1;
    } else {
      for (int bb = 0; bb < 8; ++bb){
        scal[OS_BETA + bb]  = scal[OS_RSNEW + bb] / (scal[OS_RSOLD + bb] + 1e-12f);
        scal[OS_RSOLD + bb] = scal[OS_RSNEW + bb];
        scal[OS_PAP + bb]   = 0.f;
      }
    }
  }
}

__global__ void k_pupd_o(const float* __restrict__ r, float* __restrict__ p,
                         float* scal, int n4){
  const int* flag = (const int*)(scal + OS_FLAG);
  if (*flag) return;
  int b = blockIdx.y;
  size_t base = (size_t)b * n4;
  float be = scal[OS_BETA + b];
  int j = blockIdx.x * blockDim.x + threadIdx.x;
  if (j < n4){
    f4 rv = ((const f4*)r)[base + j];
    f4 pv = ((f4*)p)[base + j];
    pv = rv + be * pv;
    ((f4*)p)[base + j] = pv;
  }
}

// ---------------- launch ----------------
extern "C" void kernel_launch(void* const* d_in, const int* in_sizes, int n_in,
                              void* d_out, int out_size, void* d_ws, size_t ws_size,
                              hipStream_t stream){
  const float* c0  = (const float*)d_in[0];
  const int*   src = (const int*)d_in[1];
  const int*   dst = (const int*)d_in[2];
  const float* Rs  = (const float*)d_in[3];
  const float* Rd  = (const float*)d_in[4];

  int N  = in_sizes[0];          // B*Mn*8 floats, B=8, d=8
  int Mn = N / 64;
  int E  = in_sizes[1];
  int n4tot = N / 4;
  int twoE = 2 * E;

  float* ws = (float*)d_ws;
  size_t off = 0;
  float* r    = ws + off;  off += N;
  float* p    = ws + off;  off += N;
  float* Ap   = ws + off;  off += N;
  float* scal = ws + off;  off += SCAL_F;
  float* Dd   = ws + off;  off += (size_t)Mn * 64;
  int* rowptr = (int*)(ws + off);  off += (size_t)((Mn + 1 + 3) & ~3);
  int* cursor = (int*)(ws + off);  off += (size_t)((Mn + 3) & ~3);
  int* colA   = (int*)(ws + off);  off += (size_t)twoE;
  int* esA    = (int*)(ws + off);  off += (size_t)twoE;
  float* Mb   = ws + off;  off += (size_t)E * 64;
  size_t need_main = off * 4;

  int nb_vec  = (n4tot + 255) / 256;
  int nb_node = (Mn * 64 + 255) / 256;

  if (ws_size >= need_main){
    k_setup_nm<<<2048, 256, 0, stream>>>(Dd, scal, cursor, Mn);
    k_deg  <<<1024, 256, 0, stream>>>(src, dst, cursor, E);
    k_scan <<<1, 1024, 0, stream>>>(cursor, rowptr, cursor, Mn, twoE);
    k_fill <<<1024, 256, 0, stream>>>(src, dst, cursor, colA, esA, E);
    k_edgeM<<<4096, 256, 0, stream>>>(Rs, Rd, src, dst, Mb, Dd, E);

    float* x_bm = (float*)d_out;
    k_perm<<<nb_vec, 256, 0, stream>>>(c0, p, Mn);   // p := c0 (node-major)
    k_mv<<<nb_node, 256, 0, stream>>>(Mb, Dd, rowptr, colA, esA, p, Ap, scal, Mn);
    k_init_nm<<<nb_vec, 256, 0, stream>>>(p, Ap, r, x_bm, scal, n4tot, Mn);
    k_s0<<<1, 256, 0, stream>>>(scal);

    for (int it = 0; it < NIT; ++it){
      k_mv<<<nb_node, 256, 0, stream>>>(Mb, Dd, rowptr, colA, esA, p, Ap, scal, Mn);
      k_upd_nm<<<nb_vec, 256, 0, stream>>>(x_bm, r, p, Ap, scal, n4tot, Mn);
      k_s2<<<1, 256, 0, stream>>>(scal);
      k_pupd_nm<<<nb_vec, 256, 0, stream>>>(r, p, scal, n4tot);
    }
  } else {
    // fallback: batch-major R-direct (needs 3N+64 floats)
    float* fr    = ws;
    float* fp    = fr + N;
    float* fAp   = fp + N;
    float* fscal = fAp + N;
    const int* flagp = (const int*)(fscal + OS_FLAG);
    int n4 = Mn * 2;
    dim3 vgrid((n4 + 255) / 256, 8);
    int cb = (n4tot + 255) / 256;
    float* x = (float*)d_out;

    k_setup_fb<<<1, 64, 0, stream>>>(fscal);
    k_apinit<<<cb, 256, 0, stream>>>(c0, fAp, n4tot, flagp);
    k_mv_edge_fb<<<2048, 256, 0, stream>>>(Rs, Rd, src, dst, c0, fAp, Mn, E, flagp);
    k_init_o<<<vgrid, 256, 0, stream>>>(c0, fAp, x, fr, fp, fscal, n4);
    for (int it = 0; it < NIT; ++it){
      k_apinit<<<cb, 256, 0, stream>>>(fp, fAp, n4tot, flagp);
      k_mv_edge_fb<<<2048, 256, 0, stream>>>(Rs, Rd, src, dst, fp, fAp, Mn, E, flagp);
      k_dot_o<<<vgrid, 256, 0, stream>>>(fp, fAp, fscal, n4);
      k_s1_o<<<1, 64, 0, stream>>>(fscal);
      k_upd_o<<<vgrid, 256, 0, stream>>>(x, fr, fp, fAp, fscal, n4);
      k_s2_o<<<1, 64, 0, stream>>>(fscal);
      k_pupd_o<<<vgrid, 256, 0, stream>>>(fr, fp, fscal, n4);
    }
  }
}